// Round 4
// baseline (525.055 us; speedup 1.0000x reference)
//
#include <hip/hip_runtime.h>
#include <math.h>

#define BATCH 32
#define HH 1024
#define WW 1024
#define WR 513
#define NPIX (HH * WR)
#define TWO_PI_F 6.28318530717958647692f

// Same-wave LDS fence: each wave only touches its own LDS region, so a full
// block barrier is unnecessary — wait for this wave's own LDS ops instead.
#define LGKM_SYNC() __asm__ __volatile__("s_waitcnt lgkmcnt(0)" ::: "memory")

__device__ __forceinline__ float2 cadd(float2 a, float2 b) { return make_float2(a.x + b.x, a.y + b.y); }
__device__ __forceinline__ float2 csub(float2 a, float2 b) { return make_float2(a.x - b.x, a.y - b.y); }
__device__ __forceinline__ float2 cmul(float2 a, float2 b) {
    return make_float2(a.x * b.x - a.y * b.y, a.x * b.y + a.y * b.x);
}

// atan2 via odd minimax poly on [0,1] (max err ~1e-5 rad) + quadrant fixup.
__device__ __forceinline__ float fast_atan2f(float y, float x) {
    float ax = __builtin_fabsf(x), ay = __builtin_fabsf(y);
    float mx = fmaxf(ax, ay), mn = fminf(ax, ay);
    float a = mn * __builtin_amdgcn_rcpf(mx);
    float s = a * a;
    float r = fmaf(fmaf(fmaf(fmaf(0.0208351f, s, -0.085133f), s, 0.180141f),
                        s, -0.3302995f), s, 0.999866f) * a;
    if (ay > ax) r = 1.5707963268f - r;
    if (x < 0.0f) r = 3.1415926536f - r;
    return (y < 0.0f) ? -r : r;
}

// Register-renaming permutation of the in-place DIF FFT16 output:
// after fft16_ip, slot[ridx(k)] holds X[k]. ridx is an involution
// (2-bit digit swap), compile-time only — zero instructions.
__device__ __forceinline__ constexpr int ridx(int k) { return ((k & 3) << 2) | (k >> 2); }

// In-place radix-4 DIF 16-point FFT. Natural-order input d[0..15];
// output digit-reversed: d[ridx(k)] = X[k].
__device__ __forceinline__ void fft16_ip(float2* d) {
    const float2 Wt1[4] = {{1.f, 0.f},
                           {0.92387953f, -0.38268343f},
                           {0.70710678f, -0.70710678f},
                           {0.38268343f, -0.92387953f}};
    const float2 Wt2[4] = {{1.f, 0.f},
                           {0.70710678f, -0.70710678f},
                           {0.f, -1.f},
                           {-0.70710678f, -0.70710678f}};
    const float2 Wt3[4] = {{1.f, 0.f},
                           {0.38268343f, -0.92387953f},
                           {-0.70710678f, -0.70710678f},
                           {-0.92387953f, 0.38268343f}};
#pragma unroll
    for (int t = 0; t < 4; ++t) {
        float2 x0 = d[t], x1 = d[t + 4], x2 = d[t + 8], x3 = d[t + 12];
        float2 a0 = cadd(x0, x2), a1 = csub(x0, x2), a2 = cadd(x1, x3), a3 = csub(x1, x3);
        d[t]      = cadd(a0, a2);
        d[t + 4]  = cmul(make_float2(a1.x + a3.y, a1.y - a3.x), Wt1[t]);
        d[t + 8]  = cmul(csub(a0, a2), Wt2[t]);
        d[t + 12] = cmul(make_float2(a1.x - a3.y, a1.y + a3.x), Wt3[t]);
    }
#pragma unroll
    for (int r = 0; r < 4; ++r) {
        float2 x0 = d[4 * r], x1 = d[4 * r + 1], x2 = d[4 * r + 2], x3 = d[4 * r + 3];
        float2 e0 = cadd(x0, x2), e1 = csub(x0, x2), e2 = cadd(x1, x3), e3 = csub(x1, x3);
        d[4 * r]     = cadd(e0, e2);
        d[4 * r + 1] = make_float2(e1.x + e3.y, e1.y - e3.x);
        d[4 * r + 2] = csub(e0, e2);
        d[4 * r + 3] = make_float2(e1.x - e3.y, e1.y + e3.x);
    }
}

// Log-depth (4) twiddle power tree: Wt[k] = T^k, k=1..15. (row_fft only —
// col_fft uses the serial chain to stay under its VGPR budget.)
__device__ __forceinline__ void twiddle_tree(float2 T, float2* Wt) {
    Wt[1] = T;
    Wt[2] = cmul(T, T);
    Wt[3] = cmul(Wt[2], T);
    Wt[4] = cmul(Wt[2], Wt[2]);
    Wt[5] = cmul(Wt[4], Wt[1]);
    Wt[6] = cmul(Wt[4], Wt[2]);
    Wt[7] = cmul(Wt[4], Wt[3]);
    Wt[8] = cmul(Wt[4], Wt[4]);
    Wt[9]  = cmul(Wt[8], Wt[1]);
    Wt[10] = cmul(Wt[8], Wt[2]);
    Wt[11] = cmul(Wt[8], Wt[3]);
    Wt[12] = cmul(Wt[8], Wt[4]);
    Wt[13] = cmul(Wt[8], Wt[5]);
    Wt[14] = cmul(Wt[8], Wt[6]);
    Wt[15] = cmul(Wt[8], Wt[7]);
}

// Wave-level 1024-pt FFT (single row — used by row_fft_kernel).
// Output: v[ridx(m)] = X[(lane&15) + 16*m + 256*kq], kq = 2*((lane>>4)&1) + ((lane>>5)&1).
__device__ __forceinline__ void wave_fft1024(float2* v, float2* sb, int lane) {
    fft16_ip(v);                      // v[ridx(k2)] = V[k2]
    float s, c;
    __sincosf(-TWO_PI_F * (float)lane * (1.0f / 1024.0f), &s, &c);
    float2 Wt[16];
    twiddle_tree(make_float2(c, s), Wt);
#pragma unroll
    for (int k2 = 1; k2 < 16; ++k2) v[ridx(k2)] = cmul(v[ridx(k2)], Wt[k2]);
    // 16x64 transpose, one float2 pass, XOR-swizzled columns.
    const int k2p = lane & 15, qp = lane >> 4;
#pragma unroll
    for (int k2 = 0; k2 < 16; ++k2) sb[(k2 << 6) | (lane ^ k2)] = v[ridx(k2)];
    LGKM_SYNC();
#pragma unroll
    for (int m = 0; m < 16; ++m) v[m] = sb[(k2p << 6) | ((4 * m + qp) ^ k2p)];
    LGKM_SYNC();                      // scratch reusable by caller after return
    fft16_ip(v);                      // v[ridx(km)] = Y[km]
    __sincosf(-TWO_PI_F * (float)qp * (1.0f / 64.0f), &s, &c);
    twiddle_tree(make_float2(c, s), Wt);
#pragma unroll
    for (int km = 1; km < 16; ++km) v[ridx(km)] = cmul(v[ridx(km)], Wt[km]);
    const bool hi2 = (lane & 32) != 0, hi1 = (lane & 16) != 0;
#pragma unroll
    for (int m = 0; m < 16; ++m) {   // slot-wise: any order
        float2 a = v[m];
        float2 o = make_float2(__shfl_xor(a.x, 32, 64), __shfl_xor(a.y, 32, 64));
        float2 s1 = hi2 ? csub(o, a) : cadd(a, o);
        if (hi2 && hi1) s1 = make_float2(s1.y, -s1.x);
        float2 o2 = make_float2(__shfl_xor(s1.x, 16, 64), __shfl_xor(s1.y, 16, 64));
        v[m] = hi1 ? csub(o2, s1) : cadd(s1, o2);
    }
}

// ---------------------------------------------------------------------------
// Kernel A: 4 waves/block, each wave = 2 packed real rows -> 1 complex FFT.
// One block barrier total. (unchanged round-2 structure — it measured faster)
// ---------------------------------------------------------------------------
__global__ __launch_bounds__(256, 4) void row_fft_kernel(const float* __restrict__ x,
                                                         float2* __restrict__ rf2) {
    __shared__ float2 buf[4][1024];
    const int t = threadIdx.x, w = t >> 6, lane = t & 63;
    const int b = blockIdx.x >> 7;
    const int h0 = (blockIdx.x & 127) * 8;
    const float* r0 = x + ((long long)b * HH + h0 + 2 * w) * (long long)WW;
    const float* r1 = r0 + WW;
    float2 v[16];
#pragma unroll
    for (int j = 0; j < 16; ++j) v[j] = make_float2(r0[lane + 64 * j], r1[lane + 64 * j]);
    float2* mybuf = &buf[w][0];
    wave_fft1024(v, mybuf, lane);
    const int kq = 2 * ((lane >> 4) & 1) + ((lane >> 5) & 1);
    const int kbase = (lane & 15) + 256 * kq;
#pragma unroll
    for (int m = 0; m < 16; ++m) mybuf[kbase + 16 * m] = v[ridx(m)];
    __syncthreads();
    for (int idx = t; idx < 513 * 8; idx += 256) {
        int k = idx >> 3, j = idx & 7, p = j >> 1, which = j & 1;
        float2 zk = buf[p][k];
        float2 zn = buf[p][(1024 - k) & 1023];
        float2 val = which ? make_float2(0.5f * (zk.y + zn.y), 0.5f * (zn.x - zk.x))
                           : make_float2(0.5f * (zk.x + zn.x), 0.5f * (zk.y - zn.y));
        rf2[((long long)b * WR + k) * 1024 + h0 + j] = val;
    }
}

// ---------------------------------------------------------------------------
// Kernel B: PERSISTENT-PIPELINED col FFT. Each wave owns 4 consecutive rows
// and software-pipelines them: issue the 16 global loads for row r+1 BEFORE
// computing row r, so the ~700-cyc LLC/HBM latency hides under the ~3600-cyc
// FFT of the previous row (T14 issue-early/use-late). Rounds 0-3 showed the
// kernel is load-latency-bound (VALUBusy 16-19%, HBM 9%, occ-insensitive):
// TLP route spills (R1), same-row ILP doesn't cover the up-front load wait
// (R3). Per-row VGPR budget forces the serial twiddle chain (no Wt[16]
// table) and the proven conflict-free two-pass b32 stride-68 transpose:
// vcur 32 + vnext 32 + tx 16 + misc ~= 100 < (128,2)'s 128-VGPR cap.
// ---------------------------------------------------------------------------
__global__ __launch_bounds__(128, 2) void col_fft_kernel(float2* __restrict__ rf2,
                                                         float* __restrict__ magmax) {
    __shared__ float sb[2][1088];
    const int t = threadIdx.x, w = t >> 6, lane = t & 63;
    const long long gw = (long long)blockIdx.x * 2 + w;   // 0..4103
    const long long fbase = gw * 4;                        // 4 rows per wave
    float* sA = &sb[w][0];
    const int k2p = lane & 15, qp = lane >> 4;
    const bool hi2 = (lane & 32) != 0, hi1 = (lane & 16) != 0;
    const int kq = 2 * ((lane >> 4) & 1) + ((lane >> 5) & 1);
    const int hbase = (lane & 15) + 256 * kq;

    float2 vn[16];
    {
        const float2* row = rf2 + fbase * 1024;
#pragma unroll
        for (int j = 0; j < 16; ++j) vn[j] = row[lane + 64 * j];
    }
    for (int r = 0; r < 4; ++r) {
        const long long fid = fbase + r;
        float2 v[16];
#pragma unroll
        for (int j = 0; j < 16; ++j) v[j] = vn[j];   // vmcnt wait lands here
        if (r < 3) {                                  // prefetch next row NOW
            const float2* nrow = rf2 + (fid + 1) * 1024;
#pragma unroll
            for (int j = 0; j < 16; ++j) vn[j] = nrow[lane + 64 * j];
        }
        // ---- 1024-pt FFT on v (latency now hidden under previous row) ----
        fft16_ip(v);
        float s, c;
        __sincosf(-TWO_PI_F * (float)lane * (1.0f / 1024.0f), &s, &c);
        float2 T = make_float2(c, s), ww = T;
#pragma unroll
        for (int k2 = 1; k2 < 16; ++k2) { v[ridx(k2)] = cmul(v[ridx(k2)], ww); ww = cmul(ww, T); }
        // two-pass b32 transpose, stride 68 (conflict-free)
        float tx[16];
#pragma unroll
        for (int k2 = 0; k2 < 16; ++k2) sA[68 * k2 + lane] = v[ridx(k2)].x;
        LGKM_SYNC();
#pragma unroll
        for (int m = 0; m < 16; ++m) tx[m] = sA[68 * k2p + 4 * m + qp];
        LGKM_SYNC();
#pragma unroll
        for (int k2 = 0; k2 < 16; ++k2) sA[68 * k2 + lane] = v[ridx(k2)].y;
        LGKM_SYNC();
#pragma unroll
        for (int m = 0; m < 16; ++m) v[m] = make_float2(tx[m], sA[68 * k2p + 4 * m + qp]);
        LGKM_SYNC();                  // sA reusable next row iteration
        fft16_ip(v);
        __sincosf(-TWO_PI_F * (float)qp * (1.0f / 64.0f), &s, &c);
        float2 U = make_float2(c, s);
        ww = U;
#pragma unroll
        for (int km = 1; km < 16; ++km) { v[ridx(km)] = cmul(v[ridx(km)], ww); ww = cmul(ww, U); }
#pragma unroll
        for (int m = 0; m < 16; ++m) {
            float2 a = v[m];
            float2 o = make_float2(__shfl_xor(a.x, 32, 64), __shfl_xor(a.y, 32, 64));
            float2 s1 = hi2 ? csub(o, a) : cadd(a, o);
            if (hi2 && hi1) s1 = make_float2(s1.y, -s1.x);
            float2 o2 = make_float2(__shfl_xor(s1.x, 16, 64), __shfl_xor(s1.y, 16, 64));
            v[m] = hi1 ? csub(o2, s1) : cadd(s1, o2);
        }
        float* pu = (float*)(rf2 + fid * 1024);
        float mmax = 0.0f;
#pragma unroll
        for (int m = 0; m < 16; ++m) {
            float2 z = v[ridx(m)];
            mmax = fmaxf(mmax, __builtin_amdgcn_sqrtf(z.x * z.x + z.y * z.y));
            float ph = fast_atan2f(z.y, z.x);
            pu[hbase + 16 * m] = (ph < 0.0f) ? ph + TWO_PI_F : ph;
        }
#pragma unroll
        for (int off = 32; off; off >>= 1) mmax = fmaxf(mmax, __shfl_down(mmax, off));
        if (lane == 0) {
            const int b = (int)(fid / WR);
            atomicMax((int*)(magmax + b), __float_as_int(mmax));
        }
    }
}

// ---------------------------------------------------------------------------
// Kernel C: single-pass gradients + all 55 Zernike moments + mask count.
// ---------------------------------------------------------------------------
#define WRED(var, idx)                                                     \
    {                                                                      \
        float r_ = var;                                                    \
        _Pragma("unroll")                                                  \
        for (int off_ = 32; off_; off_ >>= 1) r_ += __shfl_down(r_, off_); \
        if (lane == 0) red[wv * 64 + (idx)] = r_;                          \
    }

__global__ __launch_bounds__(256, 2) void stats_kernel(float* __restrict__ pu) {
    __shared__ float red[4 * 64];
    const int b = blockIdx.y;
    const int k0 = blockIdx.x * 9;
    const float* base = pu + (long long)b * WR * 2048;
    float a00 = 0.f, a11 = 0.f, a20 = 0.f, a22 = 0.f, a31 = 0.f, a33 = 0.f,
          a40 = 0.f, a42 = 0.f, a44 = 0.f, a51 = 0.f, a53 = 0.f, a55 = 0.f,
          a60 = 0.f, a62 = 0.f, a64 = 0.f, a66 = 0.f, a71 = 0.f, a73 = 0.f,
          a75 = 0.f, a77 = 0.f, a80 = 0.f, a82 = 0.f, a84 = 0.f, a86 = 0.f,
          a88 = 0.f, a91 = 0.f, a93 = 0.f, a95 = 0.f, a97 = 0.f, a99 = 0.f;
    float b11 = 0.f, b22 = 0.f, b31 = 0.f, b33 = 0.f, b42 = 0.f, b44 = 0.f,
          b51 = 0.f, b53 = 0.f, b55 = 0.f, b62 = 0.f, b64 = 0.f, b66 = 0.f,
          b71 = 0.f, b73 = 0.f, b75 = 0.f, b77 = 0.f, b82 = 0.f, b84 = 0.f,
          b86 = 0.f, b88 = 0.f, b91 = 0.f, b93 = 0.f, b95 = 0.f, b97 = 0.f,
          b99 = 0.f;
    float sgx = 0.f, sgx2 = 0.f, sgy = 0.f, sgy2 = 0.f, cnt = 0.f;

    for (int kk = 0; kk < 9; ++kk) {
        const int k = k0 + kk;
        const float* rowc = base + (long long)k * 2048;
        const float* rowm = rowc - 2048;
        const float* rowp = rowc + 2048;
        const float xv = -1.0f + (1.0f / 256.0f) * (float)k;
        const float xv2 = xv * xv;
        for (int h = threadIdx.x; h < 1024; h += 256) {
            float v = rowc[h];
            float gx, gy;
            if (k == 0)            gx = rowp[h] - v;
            else if (k == WR - 1)  gx = v - rowm[h];
            else                   gx = 0.5f * (rowp[h] - rowm[h]);
            if (h == 0)            gy = rowc[1] - v;
            else if (h == 1023)    gy = v - rowc[1022];
            else                   gy = 0.5f * (rowc[h + 1] - rowc[h - 1]);
            sgx += gx; sgx2 += gx * gx; sgy += gy; sgy2 += gy * gy;

            const float yv = -1.0f + (2.0f / 1023.0f) * (float)h;
            const float r2 = xv2 + yv * yv;
            if (r2 <= 1.0f) {
                cnt += 1.0f;
                const float rho = sqrtf(r2);
                const float inv = rsqrtf(r2);
                const float c1 = xv * inv;
                const float s1 = yv * inv;
                const float c2 = 2.f * c1 * c1 - 1.f;
                const float c3 = 2.f * c1 * c2 - c1;
                const float c4 = 2.f * c1 * c3 - c2;
                const float c5 = 2.f * c1 * c4 - c3;
                const float c6 = 2.f * c1 * c5 - c4;
                const float c7 = 2.f * c1 * c6 - c5;
                const float c8 = 2.f * c1 * c7 - c6;
                const float c9 = 2.f * c1 * c8 - c7;
                const float s2 = 2.f * c1 * s1;
                const float s3 = 2.f * c1 * s2 - s1;
                const float s4 = 2.f * c1 * s3 - s2;
                const float s5 = 2.f * c1 * s4 - s3;
                const float s6 = 2.f * c1 * s5 - s4;
                const float s7 = 2.f * c1 * s6 - s5;
                const float s8 = 2.f * c1 * s7 - s6;
                const float s9 = 2.f * c1 * s8 - s7;
                const float w0 = v,        w1 = w0 * rho, w2 = w1 * rho, w3 = w2 * rho,
                            w4 = w3 * rho, w5 = w4 * rho, w6 = w5 * rho, w7 = w6 * rho,
                            w8 = w7 * rho, w9 = w8 * rho;
                a00 += w0;
                a11 += w1 * c1;
                a20 += w2;      a22 += w2 * c2;
                a31 += w3 * c1; a33 += w3 * c3;
                a40 += w4;      a42 += w4 * c2; a44 += w4 * c4;
                a51 += w5 * c1; a53 += w5 * c3; a55 += w5 * c5;
                a60 += w6;      a62 += w6 * c2; a64 += w6 * c4; a66 += w6 * c6;
                a71 += w7 * c1; a73 += w7 * c3; a75 += w7 * c5; a77 += w7 * c7;
                a80 += w8;      a82 += w8 * c2; a84 += w8 * c4; a86 += w8 * c6; a88 += w8 * c8;
                a91 += w9 * c1; a93 += w9 * c3; a95 += w9 * c5; a97 += w9 * c7; a99 += w9 * c9;
                b11 += w1 * s1;
                b22 += w2 * s2;
                b31 += w3 * s1; b33 += w3 * s3;
                b42 += w4 * s2; b44 += w4 * s4;
                b51 += w5 * s1; b53 += w5 * s3; b55 += w5 * s5;
                b62 += w6 * s2; b64 += w6 * s4; b66 += w6 * s6;
                b71 += w7 * s1; b73 += w7 * s3; b75 += w7 * s5; b77 += w7 * s7;
                b82 += w8 * s2; b84 += w8 * s4; b86 += w8 * s6; b88 += w8 * s8;
                b91 += w9 * s1; b93 += w9 * s3; b95 += w9 * s5; b97 += w9 * s7; b99 += w9 * s9;
            }
        }
    }

    const int wv = threadIdx.x >> 6, lane = threadIdx.x & 63;
    WRED(a00, 0);  WRED(a11, 1);  WRED(a20, 2);  WRED(a22, 3);  WRED(a31, 4);
    WRED(a33, 5);  WRED(a40, 6);  WRED(a42, 7);  WRED(a44, 8);  WRED(a51, 9);
    WRED(a53, 10); WRED(a55, 11); WRED(a60, 12); WRED(a62, 13); WRED(a64, 14);
    WRED(a66, 15); WRED(a71, 16); WRED(a73, 17); WRED(a75, 18); WRED(a77, 19);
    WRED(a80, 20); WRED(a82, 21); WRED(a84, 22); WRED(a86, 23); WRED(a88, 24);
    WRED(a91, 25); WRED(a93, 26); WRED(a95, 27); WRED(a97, 28); WRED(a99, 29);
    WRED(b11, 30); WRED(b22, 31); WRED(b31, 32); WRED(b33, 33); WRED(b42, 34);
    WRED(b44, 35); WRED(b51, 36); WRED(b53, 37); WRED(b55, 38); WRED(b62, 39);
    WRED(b64, 40); WRED(b66, 41); WRED(b71, 42); WRED(b73, 43); WRED(b75, 44);
    WRED(b77, 45); WRED(b82, 46); WRED(b84, 47); WRED(b86, 48); WRED(b88, 49);
    WRED(b91, 50); WRED(b93, 51); WRED(b95, 52); WRED(b97, 53); WRED(b99, 54);
    WRED(sgx, 55); WRED(sgx2, 56); WRED(sgy, 57); WRED(sgy2, 58); WRED(cnt, 59);
    __syncthreads();
    const int t = threadIdx.x;
    if (t < 60) {
        float s = red[t] + red[64 + t] + red[128 + t] + red[192 + t];
        pu[((long long)(b * 57 + blockIdx.x)) * 2048 + 1024 + t] = s;
    }
}

// ---------------------------------------------------------------------------
// Kernel D: sum 57 block-partials per batch, map moments -> Zernike coeffs,
// finalize stats.
// ---------------------------------------------------------------------------
__device__ int moment_index(int p, int a, int is_cos) {
    int ai = 0;
    for (int pp = 0; pp < 10; ++pp)
        for (int aa = (pp & 1); aa <= pp; aa += 2) {
            if (is_cos && pp == p && aa == a) return ai;
            ++ai;
        }
    for (int pp = 1; pp < 10; ++pp)
        for (int aa = ((pp & 1) ? 1 : 2); aa <= pp; aa += 2) {
            if (!is_cos && pp == p && aa == a) return ai;
            ++ai;
        }
    return 0;
}

__device__ float factf(int n) {
    float f = 1.0f;
    for (int i = 2; i <= n; ++i) f *= (float)i;
    return f;
}

__global__ void finalize_kernel(const float* __restrict__ pu,
                                const float* __restrict__ magmax,
                                float* __restrict__ out) {
    __shared__ float abf[64];
    const int b = blockIdx.x;
    const int j = threadIdx.x;
    if (j < 60) {
        float s = 0.0f;
        for (int i = 0; i < 57; ++i)
            s += pu[((long long)(b * 57 + i)) * 2048 + 1024 + j];
        abf[j] = s;
    }
    __syncthreads();
    if (j >= 60) return;
    const float NF = (float)NPIX;
    float val;
    if (j < 55) {
        int tt = j, n = 0;
        while (tt >= n + 1) { tt -= (n + 1); ++n; }
        int m = -n + 2 * tt;
        int am = m < 0 ? -m : m;
        float s = 0.0f;
        for (int k = 0; k <= (n - am) / 2; ++k) {
            float c = factf(n - k) /
                      (factf(k) * factf((n + am) / 2 - k) * factf((n - am) / 2 - k));
            if (k & 1) c = -c;
            int p = n - 2 * k;
            s += c * abf[moment_index(p, am, m >= 0 ? 1 : 0)];
        }
        val = s / abf[59];
    } else if (j == 55) {
        val = abf[55] / NF;
    } else if (j == 56) {
        val = abf[57] / NF;
    } else if (j == 57) {
        float sum = abf[55], sq = abf[56];
        val = sqrtf(fmaxf(0.0f, (sq - sum * sum / NF) / (NF - 1.0f)));
    } else if (j == 58) {
        float sum = abf[57], sq = abf[58];
        val = sqrtf(fmaxf(0.0f, (sq - sum * sum / NF) / (NF - 1.0f)));
    } else {
        val = magmax[b];
    }
    out[b * 60 + j] = val;
}

// ---------------------------------------------------------------------------
extern "C" void kernel_launch(void* const* d_in, const int* in_sizes, int n_in,
                              void* d_out, int out_size, void* d_ws, size_t ws_size,
                              hipStream_t stream) {
    (void)in_sizes; (void)n_in; (void)out_size; (void)ws_size;
    const float* x = (const float*)d_in[0];
    float* out = (float*)d_out;

    float* magmax = (float*)d_ws;                  // 32 floats (atomicMax target)
    float2* rf2 = (float2*)((char*)d_ws + 16384);  // [B][WR][H] float2 = 134.5 MB

    hipMemsetAsync(d_ws, 0, 16384, stream);
    row_fft_kernel<<<BATCH * 128, 256, 0, stream>>>(x, rf2);
    // 16416 rows / 4 rows-per-wave = 4104 waves = 2052 blocks of 2 waves
    col_fft_kernel<<<2052, 128, 0, stream>>>(rf2, magmax);
    dim3 gridC(57, BATCH);
    stats_kernel<<<gridC, 256, 0, stream>>>((float*)rf2);
    finalize_kernel<<<BATCH, 64, 0, stream>>>((const float*)rf2, magmax, out);
}

// Round 5
// 519.659 us; speedup vs baseline: 1.0104x; 1.0104x over previous
//
#include <hip/hip_runtime.h>
#include <math.h>

#define BATCH 32
#define HH 1024
#define WW 1024
#define WR 513
#define NPIX (HH * WR)
#define TWO_PI_F 6.28318530717958647692f

// Same-wave LDS fences. Full stop:
#define LGKM_SYNC() __asm__ __volatile__("s_waitcnt lgkmcnt(0)" ::: "memory")
// Counted: wait until <= N of this wave's LDS ops remain outstanding (DS in-order).
#define LGKM_CNT(n) __asm__ __volatile__("s_waitcnt lgkmcnt(" #n ")" ::: "memory")
#define SCHED_PIN() __builtin_amdgcn_sched_barrier(0)

__device__ __forceinline__ float2 cadd(float2 a, float2 b) { return make_float2(a.x + b.x, a.y + b.y); }
__device__ __forceinline__ float2 csub(float2 a, float2 b) { return make_float2(a.x - b.x, a.y - b.y); }
__device__ __forceinline__ float2 cmul(float2 a, float2 b) {
    return make_float2(a.x * b.x - a.y * b.y, a.x * b.y + a.y * b.x);
}

// atan2 via odd minimax poly on [0,1] (max err ~1e-5 rad) + quadrant fixup.
__device__ __forceinline__ float fast_atan2f(float y, float x) {
    float ax = __builtin_fabsf(x), ay = __builtin_fabsf(y);
    float mx = fmaxf(ax, ay), mn = fminf(ax, ay);
    float a = mn * __builtin_amdgcn_rcpf(mx);
    float s = a * a;
    float r = fmaf(fmaf(fmaf(fmaf(0.0208351f, s, -0.085133f), s, 0.180141f),
                        s, -0.3302995f), s, 0.999866f) * a;
    if (ay > ax) r = 1.5707963268f - r;
    if (x < 0.0f) r = 3.1415926536f - r;
    return (y < 0.0f) ? -r : r;
}

// Register-renaming permutation of the in-place DIF FFT16 output:
// after fft16_ip, slot[ridx(k)] holds X[k]. Compile-time only.
__device__ __forceinline__ constexpr int ridx(int k) { return ((k & 3) << 2) | (k >> 2); }

// In-place radix-4 DIF 16-point FFT. Natural-order input d[0..15];
// output digit-reversed: d[ridx(k)] = X[k].
__device__ __forceinline__ void fft16_ip(float2* d) {
    const float2 Wt1[4] = {{1.f, 0.f},
                           {0.92387953f, -0.38268343f},
                           {0.70710678f, -0.70710678f},
                           {0.38268343f, -0.92387953f}};
    const float2 Wt2[4] = {{1.f, 0.f},
                           {0.70710678f, -0.70710678f},
                           {0.f, -1.f},
                           {-0.70710678f, -0.70710678f}};
    const float2 Wt3[4] = {{1.f, 0.f},
                           {0.38268343f, -0.92387953f},
                           {-0.70710678f, -0.70710678f},
                           {-0.92387953f, 0.38268343f}};
#pragma unroll
    for (int t = 0; t < 4; ++t) {
        float2 x0 = d[t], x1 = d[t + 4], x2 = d[t + 8], x3 = d[t + 12];
        float2 a0 = cadd(x0, x2), a1 = csub(x0, x2), a2 = cadd(x1, x3), a3 = csub(x1, x3);
        d[t]      = cadd(a0, a2);
        d[t + 4]  = cmul(make_float2(a1.x + a3.y, a1.y - a3.x), Wt1[t]);
        d[t + 8]  = cmul(csub(a0, a2), Wt2[t]);
        d[t + 12] = cmul(make_float2(a1.x - a3.y, a1.y + a3.x), Wt3[t]);
    }
#pragma unroll
    for (int r = 0; r < 4; ++r) {
        float2 x0 = d[4 * r], x1 = d[4 * r + 1], x2 = d[4 * r + 2], x3 = d[4 * r + 3];
        float2 e0 = cadd(x0, x2), e1 = csub(x0, x2), e2 = cadd(x1, x3), e3 = csub(x1, x3);
        d[4 * r]     = cadd(e0, e2);
        d[4 * r + 1] = make_float2(e1.x + e3.y, e1.y - e3.x);
        d[4 * r + 2] = csub(e0, e2);
        d[4 * r + 3] = make_float2(e1.x - e3.y, e1.y + e3.x);
    }
}

// Log-depth twiddle power tree (row_fft only).
__device__ __forceinline__ void twiddle_tree(float2 T, float2* Wt) {
    Wt[1] = T;
    Wt[2] = cmul(T, T);
    Wt[3] = cmul(Wt[2], T);
    Wt[4] = cmul(Wt[2], Wt[2]);
    Wt[5] = cmul(Wt[4], Wt[1]);
    Wt[6] = cmul(Wt[4], Wt[2]);
    Wt[7] = cmul(Wt[4], Wt[3]);
    Wt[8] = cmul(Wt[4], Wt[4]);
    Wt[9]  = cmul(Wt[8], Wt[1]);
    Wt[10] = cmul(Wt[8], Wt[2]);
    Wt[11] = cmul(Wt[8], Wt[3]);
    Wt[12] = cmul(Wt[8], Wt[4]);
    Wt[13] = cmul(Wt[8], Wt[5]);
    Wt[14] = cmul(Wt[8], Wt[6]);
    Wt[15] = cmul(Wt[8], Wt[7]);
}

// Wave-level 1024-pt FFT (single row — used by row_fft_kernel).
__device__ __forceinline__ void wave_fft1024(float2* v, float2* sb, int lane) {
    fft16_ip(v);
    float s, c;
    __sincosf(-TWO_PI_F * (float)lane * (1.0f / 1024.0f), &s, &c);
    float2 Wt[16];
    twiddle_tree(make_float2(c, s), Wt);
#pragma unroll
    for (int k2 = 1; k2 < 16; ++k2) v[ridx(k2)] = cmul(v[ridx(k2)], Wt[k2]);
    const int k2p = lane & 15, qp = lane >> 4;
#pragma unroll
    for (int k2 = 0; k2 < 16; ++k2) sb[(k2 << 6) | (lane ^ k2)] = v[ridx(k2)];
    LGKM_SYNC();
#pragma unroll
    for (int m = 0; m < 16; ++m) v[m] = sb[(k2p << 6) | ((4 * m + qp) ^ k2p)];
    LGKM_SYNC();
    fft16_ip(v);
    __sincosf(-TWO_PI_F * (float)qp * (1.0f / 64.0f), &s, &c);
    twiddle_tree(make_float2(c, s), Wt);
#pragma unroll
    for (int km = 1; km < 16; ++km) v[ridx(km)] = cmul(v[ridx(km)], Wt[km]);
    const bool hi2 = (lane & 32) != 0, hi1 = (lane & 16) != 0;
#pragma unroll
    for (int m = 0; m < 16; ++m) {
        float2 a = v[m];
        float2 o = make_float2(__shfl_xor(a.x, 32, 64), __shfl_xor(a.y, 32, 64));
        float2 s1 = hi2 ? csub(o, a) : cadd(a, o);
        if (hi2 && hi1) s1 = make_float2(s1.y, -s1.x);
        float2 o2 = make_float2(__shfl_xor(s1.x, 16, 64), __shfl_xor(s1.y, 16, 64));
        v[m] = hi1 ? csub(o2, s1) : cadd(s1, o2);
    }
}

// ---------------------------------------------------------------------------
// Kernel A: unchanged round-2 structure (it measured faster than round-0's).
// ---------------------------------------------------------------------------
__global__ __launch_bounds__(256, 4) void row_fft_kernel(const float* __restrict__ x,
                                                         float2* __restrict__ rf2) {
    __shared__ float2 buf[4][1024];
    const int t = threadIdx.x, w = t >> 6, lane = t & 63;
    const int b = blockIdx.x >> 7;
    const int h0 = (blockIdx.x & 127) * 8;
    const float* r0 = x + ((long long)b * HH + h0 + 2 * w) * (long long)WW;
    const float* r1 = r0 + WW;
    float2 v[16];
#pragma unroll
    for (int j = 0; j < 16; ++j) v[j] = make_float2(r0[lane + 64 * j], r1[lane + 64 * j]);
    float2* mybuf = &buf[w][0];
    wave_fft1024(v, mybuf, lane);
    const int kq = 2 * ((lane >> 4) & 1) + ((lane >> 5) & 1);
    const int kbase = (lane & 15) + 256 * kq;
#pragma unroll
    for (int m = 0; m < 16; ++m) mybuf[kbase + 16 * m] = v[ridx(m)];
    __syncthreads();
    for (int idx = t; idx < 513 * 8; idx += 256) {
        int k = idx >> 3, j = idx & 7, p = j >> 1, which = j & 1;
        float2 zk = buf[p][k];
        float2 zn = buf[p][(1024 - k) & 1023];
        float2 val = which ? make_float2(0.5f * (zk.y + zn.y), 0.5f * (zn.x - zk.x))
                           : make_float2(0.5f * (zk.x + zn.x), 0.5f * (zk.y - zn.y));
        rf2[((long long)b * WR + k) * 1024 + h0 + j] = val;
    }
}

// ---------------------------------------------------------------------------
// Kernel B: STAGGERED dual-row col FFT. R0-R4 showed col_fft insensitive to
// occupancy, prefetch depth, DS-op count, and bank conflicts (all pipes <20%
// busy) — the remaining suspect is the intra-wave serial fence structure
// (every LDS write was immediately followed by lgkm(0)+read with nothing in
// between). Here the two rows are OFFSET by half a pipeline stage: row B's
// fft fills row A's write->read LDS round trip, row A's second fft covers
// row B's writes, A's epilogue covers B's reads. Counted lgkm(15) keeps B's
// writes in flight across A's read-wait. sched_barrier(0) pins each DS issue
// group so hipcc can't hoist the coverage VALU above it.
// ---------------------------------------------------------------------------
__global__ __launch_bounds__(128, 2) void col_fft_kernel(float2* __restrict__ rf2,
                                                         float* __restrict__ magmax) {
    __shared__ float2 sb[2][2][1024];   // [wave][row][1024] = 32 KB
    const int t = threadIdx.x, w = t >> 6, lane = t & 63;
    const long long pair = (long long)blockIdx.x * 2 + w;   // 0..8207
    const long long fidA = pair * 2, fidB = fidA + 1;
    float2* rowA = rf2 + fidA * 1024;
    float2* rowB = rf2 + fidB * 1024;
    const int k2p = lane & 15, qp = lane >> 4;
    const bool hi2 = (lane & 32) != 0, hi1 = (lane & 16) != 0;
    const int kq = 2 * ((lane >> 4) & 1) + ((lane >> 5) & 1);
    const int hbase = (lane & 15) + 256 * kq;
    float2* sA = &sb[w][0][0];
    float2* sB = &sb[w][1][0];

    float2 va[16], vb[16];
#pragma unroll
    for (int j = 0; j < 16; ++j) va[j] = rowA[lane + 64 * j];
#pragma unroll
    for (int j = 0; j < 16; ++j) vb[j] = rowB[lane + 64 * j];

    // Twiddle bases shared by both rows (lane-dependent only).
    float s0, c0, s1, c1;
    __sincosf(-TWO_PI_F * (float)lane * (1.0f / 1024.0f), &s0, &c0);
    __sincosf(-TWO_PI_F * (float)qp * (1.0f / 64.0f), &s1, &c1);
    const float2 T = make_float2(c0, s0);
    const float2 U = make_float2(c1, s1);

    // --- A: fft1 + twiddle + LDS write (compiler waits vmcnt for A only) ---
    fft16_ip(va);
    {
        float2 ww = T;
#pragma unroll
        for (int k2 = 1; k2 < 16; ++k2) { va[ridx(k2)] = cmul(va[ridx(k2)], ww); ww = cmul(ww, T); }
    }
#pragma unroll
    for (int k2 = 0; k2 < 16; ++k2) sA[(k2 << 6) | (lane ^ k2)] = va[ridx(k2)];
    SCHED_PIN();
    // --- B: fft1 + twiddle (pure VALU — covers A's LDS-write latency) ---
    fft16_ip(vb);
    {
        float2 ww = T;
#pragma unroll
        for (int k2 = 1; k2 < 16; ++k2) { vb[ridx(k2)] = cmul(vb[ridx(k2)], ww); ww = cmul(ww, T); }
    }
    LGKM_SYNC();                       // A writes long since done — cheap
    // --- issue A reads, then B writes (separate LDS region) ---
#pragma unroll
    for (int m = 0; m < 16; ++m) va[m] = sA[(k2p << 6) | ((4 * m + qp) ^ k2p)];
#pragma unroll
    for (int k2 = 0; k2 < 16; ++k2) sB[(k2 << 6) | (lane ^ k2)] = vb[ridx(k2)];
    SCHED_PIN();
    LGKM_CNT(15);                      // A reads done; B writes may stay in flight
    // --- A: fft2 + twiddle + cross-lane stages (covers B's writes) ---
    fft16_ip(va);
    {
        float2 ww = U;
#pragma unroll
        for (int km = 1; km < 16; ++km) { va[ridx(km)] = cmul(va[ridx(km)], ww); ww = cmul(ww, U); }
    }
#pragma unroll
    for (int m = 0; m < 16; ++m) {
        float2 a = va[m];
        float2 o = make_float2(__shfl_xor(a.x, 32, 64), __shfl_xor(a.y, 32, 64));
        float2 t1 = hi2 ? csub(o, a) : cadd(a, o);
        if (hi2 && hi1) t1 = make_float2(t1.y, -t1.x);
        float2 o2 = make_float2(__shfl_xor(t1.x, 16, 64), __shfl_xor(t1.y, 16, 64));
        va[m] = hi1 ? csub(o2, t1) : cadd(t1, o2);
    }
    LGKM_SYNC();                       // B writes + A shfl drained
    // --- issue B reads ---
#pragma unroll
    for (int m = 0; m < 16; ++m) vb[m] = sB[(k2p << 6) | ((4 * m + qp) ^ k2p)];
    SCHED_PIN();
    // --- A epilogue (VALU + stores — covers B's read latency) ---
    float* puA = (float*)rowA;
    float mmaxA = 0.0f;
#pragma unroll
    for (int m = 0; m < 16; ++m) {
        float2 z = va[ridx(m)];
        mmaxA = fmaxf(mmaxA, __builtin_amdgcn_sqrtf(z.x * z.x + z.y * z.y));
        float ph = fast_atan2f(z.y, z.x);
        puA[hbase + 16 * m] = (ph < 0.0f) ? ph + TWO_PI_F : ph;
    }
    LGKM_SYNC();                       // B reads done
    // --- B: fft2 + twiddle + cross-lane + epilogue ---
    fft16_ip(vb);
    {
        float2 ww = U;
#pragma unroll
        for (int km = 1; km < 16; ++km) { vb[ridx(km)] = cmul(vb[ridx(km)], ww); ww = cmul(ww, U); }
    }
#pragma unroll
    for (int m = 0; m < 16; ++m) {
        float2 a = vb[m];
        float2 o = make_float2(__shfl_xor(a.x, 32, 64), __shfl_xor(a.y, 32, 64));
        float2 t1 = hi2 ? csub(o, a) : cadd(a, o);
        if (hi2 && hi1) t1 = make_float2(t1.y, -t1.x);
        float2 o2 = make_float2(__shfl_xor(t1.x, 16, 64), __shfl_xor(t1.y, 16, 64));
        vb[m] = hi1 ? csub(o2, t1) : cadd(t1, o2);
    }
    float* puB = (float*)rowB;
    float mmaxB = 0.0f;
#pragma unroll
    for (int m = 0; m < 16; ++m) {
        float2 z = vb[ridx(m)];
        mmaxB = fmaxf(mmaxB, __builtin_amdgcn_sqrtf(z.x * z.x + z.y * z.y));
        float ph = fast_atan2f(z.y, z.x);
        puB[hbase + 16 * m] = (ph < 0.0f) ? ph + TWO_PI_F : ph;
    }
#pragma unroll
    for (int off = 32; off; off >>= 1) {
        mmaxA = fmaxf(mmaxA, __shfl_down(mmaxA, off));
        mmaxB = fmaxf(mmaxB, __shfl_down(mmaxB, off));
    }
    if (lane == 0) {
        atomicMax((int*)(magmax + (int)(fidA / WR)), __float_as_int(mmaxA));
        atomicMax((int*)(magmax + (int)(fidB / WR)), __float_as_int(mmaxB));
    }
}

// ---------------------------------------------------------------------------
// Kernel C: gradients + 55 Zernike moments, float4-vectorized (G13): each
// thread handles exactly 4 consecutive pixels per k-row -> 1 float4 load
// instead of 4+ scalar loads, and 4-pixel ILP in the Chebyshev recurrences.
// ---------------------------------------------------------------------------
#define WRED(var, idx)                                                     \
    {                                                                      \
        float r_ = var;                                                    \
        _Pragma("unroll")                                                  \
        for (int off_ = 32; off_; off_ >>= 1) r_ += __shfl_down(r_, off_); \
        if (lane == 0) red[wv * 64 + (idx)] = r_;                          \
    }

// Masked Zernike accumulation for one pixel (uses enclosing-scope names).
#define ZPIX(VV, YVV)                                                          \
    {                                                                          \
        const float yv_ = (YVV);                                               \
        const float r2_ = xv2 + yv_ * yv_;                                     \
        if (r2_ <= 1.0f) {                                                     \
            cnt += 1.0f;                                                       \
            const float rho = sqrtf(r2_);                                      \
            const float inv = rsqrtf(r2_);                                     \
            const float c1 = xv * inv;                                         \
            const float s1 = yv_ * inv;                                        \
            const float c2 = 2.f * c1 * c1 - 1.f;                              \
            const float c3 = 2.f * c1 * c2 - c1;                               \
            const float c4 = 2.f * c1 * c3 - c2;                               \
            const float c5 = 2.f * c1 * c4 - c3;                               \
            const float c6 = 2.f * c1 * c5 - c4;                               \
            const float c7 = 2.f * c1 * c6 - c5;                               \
            const float c8 = 2.f * c1 * c7 - c6;                               \
            const float c9 = 2.f * c1 * c8 - c7;                               \
            const float s2 = 2.f * c1 * s1;                                    \
            const float s3 = 2.f * c1 * s2 - s1;                               \
            const float s4 = 2.f * c1 * s3 - s2;                               \
            const float s5 = 2.f * c1 * s4 - s3;                               \
            const float s6 = 2.f * c1 * s5 - s4;                               \
            const float s7 = 2.f * c1 * s6 - s5;                               \
            const float s8 = 2.f * c1 * s7 - s6;                               \
            const float s9 = 2.f * c1 * s8 - s7;                               \
            const float w0 = (VV), w1 = w0 * rho, w2 = w1 * rho, w3 = w2 * rho,\
                        w4 = w3 * rho, w5 = w4 * rho, w6 = w5 * rho,           \
                        w7 = w6 * rho, w8 = w7 * rho, w9 = w8 * rho;           \
            a00 += w0;                                                         \
            a11 += w1 * c1;                                                    \
            a20 += w2;      a22 += w2 * c2;                                    \
            a31 += w3 * c1; a33 += w3 * c3;                                    \
            a40 += w4;      a42 += w4 * c2; a44 += w4 * c4;                    \
            a51 += w5 * c1; a53 += w5 * c3; a55 += w5 * c5;                    \
            a60 += w6;      a62 += w6 * c2; a64 += w6 * c4; a66 += w6 * c6;    \
            a71 += w7 * c1; a73 += w7 * c3; a75 += w7 * c5; a77 += w7 * c7;    \
            a80 += w8;      a82 += w8 * c2; a84 += w8 * c4; a86 += w8 * c6;    \
            a88 += w8 * c8;                                                    \
            a91 += w9 * c1; a93 += w9 * c3; a95 += w9 * c5; a97 += w9 * c7;    \
            a99 += w9 * c9;                                                    \
            b11 += w1 * s1;                                                    \
            b22 += w2 * s2;                                                    \
            b31 += w3 * s1; b33 += w3 * s3;                                    \
            b42 += w4 * s2; b44 += w4 * s4;                                    \
            b51 += w5 * s1; b53 += w5 * s3; b55 += w5 * s5;                    \
            b62 += w6 * s2; b64 += w6 * s4; b66 += w6 * s6;                    \
            b71 += w7 * s1; b73 += w7 * s3; b75 += w7 * s5; b77 += w7 * s7;    \
            b82 += w8 * s2; b84 += w8 * s4; b86 += w8 * s6; b88 += w8 * s8;    \
            b91 += w9 * s1; b93 += w9 * s3; b95 += w9 * s5; b97 += w9 * s7;    \
            b99 += w9 * s9;                                                    \
        }                                                                      \
    }

__global__ __launch_bounds__(256, 2) void stats_kernel(float* __restrict__ pu) {
    __shared__ float red[4 * 64];
    const int b = blockIdx.y;
    const int k0 = blockIdx.x * 9;
    const float* base = pu + (long long)b * WR * 2048;
    float a00 = 0.f, a11 = 0.f, a20 = 0.f, a22 = 0.f, a31 = 0.f, a33 = 0.f,
          a40 = 0.f, a42 = 0.f, a44 = 0.f, a51 = 0.f, a53 = 0.f, a55 = 0.f,
          a60 = 0.f, a62 = 0.f, a64 = 0.f, a66 = 0.f, a71 = 0.f, a73 = 0.f,
          a75 = 0.f, a77 = 0.f, a80 = 0.f, a82 = 0.f, a84 = 0.f, a86 = 0.f,
          a88 = 0.f, a91 = 0.f, a93 = 0.f, a95 = 0.f, a97 = 0.f, a99 = 0.f;
    float b11 = 0.f, b22 = 0.f, b31 = 0.f, b33 = 0.f, b42 = 0.f, b44 = 0.f,
          b51 = 0.f, b53 = 0.f, b55 = 0.f, b62 = 0.f, b64 = 0.f, b66 = 0.f,
          b71 = 0.f, b73 = 0.f, b75 = 0.f, b77 = 0.f, b82 = 0.f, b84 = 0.f,
          b86 = 0.f, b88 = 0.f, b91 = 0.f, b93 = 0.f, b95 = 0.f, b97 = 0.f,
          b99 = 0.f;
    float sgx = 0.f, sgx2 = 0.f, sgy = 0.f, sgy2 = 0.f, cnt = 0.f;

    const int h4 = threadIdx.x * 4;                 // exactly one float4/thread/row
    const float yv0 = -1.0f + (2.0f / 1023.0f) * (float)h4;
    const float ystep = 2.0f / 1023.0f;

    for (int kk = 0; kk < 9; ++kk) {
        const int k = k0 + kk;
        const float* rowc = base + (long long)k * 2048;
        const float xv = -1.0f + (1.0f / 256.0f) * (float)k;
        const float xv2 = xv * xv;

        const float4 vc = *reinterpret_cast<const float4*>(rowc + h4);
        float4 gx4;
        if (k == 0) {
            const float4 vp = *reinterpret_cast<const float4*>(rowc + 2048 + h4);
            gx4 = make_float4(vp.x - vc.x, vp.y - vc.y, vp.z - vc.z, vp.w - vc.w);
        } else if (k == WR - 1) {
            const float4 vm = *reinterpret_cast<const float4*>(rowc - 2048 + h4);
            gx4 = make_float4(vc.x - vm.x, vc.y - vm.y, vc.z - vm.z, vc.w - vm.w);
        } else {
            const float4 vm = *reinterpret_cast<const float4*>(rowc - 2048 + h4);
            const float4 vp = *reinterpret_cast<const float4*>(rowc + 2048 + h4);
            gx4 = make_float4(0.5f * (vp.x - vm.x), 0.5f * (vp.y - vm.y),
                              0.5f * (vp.z - vm.z), 0.5f * (vp.w - vm.w));
        }
        const float left  = rowc[(h4 > 0) ? h4 - 1 : 0];
        const float right = rowc[(h4 < 1020) ? h4 + 4 : 1023];
        const float gy0 = (h4 == 0)    ? vc.y - vc.x : 0.5f * (vc.y - left);
        const float gy1 = 0.5f * (vc.z - vc.x);
        const float gy2 = 0.5f * (vc.w - vc.y);
        const float gy3 = (h4 == 1020) ? vc.w - vc.z : 0.5f * (right - vc.z);

        sgx  += gx4.x + gx4.y + gx4.z + gx4.w;
        sgx2 += gx4.x * gx4.x + gx4.y * gx4.y + gx4.z * gx4.z + gx4.w * gx4.w;
        sgy  += gy0 + gy1 + gy2 + gy3;
        sgy2 += gy0 * gy0 + gy1 * gy1 + gy2 * gy2 + gy3 * gy3;

        ZPIX(vc.x, yv0);
        ZPIX(vc.y, yv0 + ystep);
        ZPIX(vc.z, yv0 + 2.0f * ystep);
        ZPIX(vc.w, yv0 + 3.0f * ystep);
    }

    const int wv = threadIdx.x >> 6, lane = threadIdx.x & 63;
    WRED(a00, 0);  WRED(a11, 1);  WRED(a20, 2);  WRED(a22, 3);  WRED(a31, 4);
    WRED(a33, 5);  WRED(a40, 6);  WRED(a42, 7);  WRED(a44, 8);  WRED(a51, 9);
    WRED(a53, 10); WRED(a55, 11); WRED(a60, 12); WRED(a62, 13); WRED(a64, 14);
    WRED(a66, 15); WRED(a71, 16); WRED(a73, 17); WRED(a75, 18); WRED(a77, 19);
    WRED(a80, 20); WRED(a82, 21); WRED(a84, 22); WRED(a86, 23); WRED(a88, 24);
    WRED(a91, 25); WRED(a93, 26); WRED(a95, 27); WRED(a97, 28); WRED(a99, 29);
    WRED(b11, 30); WRED(b22, 31); WRED(b31, 32); WRED(b33, 33); WRED(b42, 34);
    WRED(b44, 35); WRED(b51, 36); WRED(b53, 37); WRED(b55, 38); WRED(b62, 39);
    WRED(b64, 40); WRED(b66, 41); WRED(b71, 42); WRED(b73, 43); WRED(b75, 44);
    WRED(b77, 45); WRED(b82, 46); WRED(b84, 47); WRED(b86, 48); WRED(b88, 49);
    WRED(b91, 50); WRED(b93, 51); WRED(b95, 52); WRED(b97, 53); WRED(b99, 54);
    WRED(sgx, 55); WRED(sgx2, 56); WRED(sgy, 57); WRED(sgy2, 58); WRED(cnt, 59);
    __syncthreads();
    const int t = threadIdx.x;
    if (t < 60) {
        float s = red[t] + red[64 + t] + red[128 + t] + red[192 + t];
        pu[((long long)(b * 57 + blockIdx.x)) * 2048 + 1024 + t] = s;
    }
}

// ---------------------------------------------------------------------------
// Kernel D: unchanged.
// ---------------------------------------------------------------------------
__device__ int moment_index(int p, int a, int is_cos) {
    int ai = 0;
    for (int pp = 0; pp < 10; ++pp)
        for (int aa = (pp & 1); aa <= pp; aa += 2) {
            if (is_cos && pp == p && aa == a) return ai;
            ++ai;
        }
    for (int pp = 1; pp < 10; ++pp)
        for (int aa = ((pp & 1) ? 1 : 2); aa <= pp; aa += 2) {
            if (!is_cos && pp == p && aa == a) return ai;
            ++ai;
        }
    return 0;
}

__device__ float factf(int n) {
    float f = 1.0f;
    for (int i = 2; i <= n; ++i) f *= (float)i;
    return f;
}

__global__ void finalize_kernel(const float* __restrict__ pu,
                                const float* __restrict__ magmax,
                                float* __restrict__ out) {
    __shared__ float abf[64];
    const int b = blockIdx.x;
    const int j = threadIdx.x;
    if (j < 60) {
        float s = 0.0f;
        for (int i = 0; i < 57; ++i)
            s += pu[((long long)(b * 57 + i)) * 2048 + 1024 + j];
        abf[j] = s;
    }
    __syncthreads();
    if (j >= 60) return;
    const float NF = (float)NPIX;
    float val;
    if (j < 55) {
        int tt = j, n = 0;
        while (tt >= n + 1) { tt -= (n + 1); ++n; }
        int m = -n + 2 * tt;
        int am = m < 0 ? -m : m;
        float s = 0.0f;
        for (int k = 0; k <= (n - am) / 2; ++k) {
            float c = factf(n - k) /
                      (factf(k) * factf((n + am) / 2 - k) * factf((n - am) / 2 - k));
            if (k & 1) c = -c;
            int p = n - 2 * k;
            s += c * abf[moment_index(p, am, m >= 0 ? 1 : 0)];
        }
        val = s / abf[59];
    } else if (j == 55) {
        val = abf[55] / NF;
    } else if (j == 56) {
        val = abf[57] / NF;
    } else if (j == 57) {
        float sum = abf[55], sq = abf[56];
        val = sqrtf(fmaxf(0.0f, (sq - sum * sum / NF) / (NF - 1.0f)));
    } else if (j == 58) {
        float sum = abf[57], sq = abf[58];
        val = sqrtf(fmaxf(0.0f, (sq - sum * sum / NF) / (NF - 1.0f)));
    } else {
        val = magmax[b];
    }
    out[b * 60 + j] = val;
}

// ---------------------------------------------------------------------------
extern "C" void kernel_launch(void* const* d_in, const int* in_sizes, int n_in,
                              void* d_out, int out_size, void* d_ws, size_t ws_size,
                              hipStream_t stream) {
    (void)in_sizes; (void)n_in; (void)out_size; (void)ws_size;
    const float* x = (const float*)d_in[0];
    float* out = (float*)d_out;

    float* magmax = (float*)d_ws;                  // 32 floats (atomicMax target)
    float2* rf2 = (float2*)((char*)d_ws + 16384);  // [B][WR][H] float2 = 134.5 MB

    hipMemsetAsync(d_ws, 0, 16384, stream);
    row_fft_kernel<<<BATCH * 128, 256, 0, stream>>>(x, rf2);
    // 16416 rows = 8208 pairs; 2 waves/block -> 4104 blocks
    col_fft_kernel<<<4104, 128, 0, stream>>>(rf2, magmax);
    dim3 gridC(57, BATCH);
    stats_kernel<<<gridC, 256, 0, stream>>>((float*)rf2);
    finalize_kernel<<<BATCH, 64, 0, stream>>>((const float*)rf2, magmax, out);
}

// Round 6
// 515.813 us; speedup vs baseline: 1.0179x; 1.0075x over previous
//
#include <hip/hip_runtime.h>
#include <math.h>

#define BATCH 32
#define HH 1024
#define WW 1024
#define WR 513
#define NPIX (HH * WR)
#define TWO_PI_F 6.28318530717958647692f

// Same-wave LDS fence: wait for this wave's own LDS ops (1-wave blocks /
// wave-private regions — no block barrier needed).
#define LGKM_SYNC() __asm__ __volatile__("s_waitcnt lgkmcnt(0)" ::: "memory")

__device__ __forceinline__ float2 cadd(float2 a, float2 b) { return make_float2(a.x + b.x, a.y + b.y); }
__device__ __forceinline__ float2 csub(float2 a, float2 b) { return make_float2(a.x - b.x, a.y - b.y); }
__device__ __forceinline__ float2 cmul(float2 a, float2 b) {
    return make_float2(a.x * b.x - a.y * b.y, a.x * b.y + a.y * b.x);
}

// atan2 via odd minimax poly on [0,1] (max err ~1e-5 rad) + quadrant fixup.
__device__ __forceinline__ float fast_atan2f(float y, float x) {
    float ax = __builtin_fabsf(x), ay = __builtin_fabsf(y);
    float mx = fmaxf(ax, ay), mn = fminf(ax, ay);
    float a = mn * __builtin_amdgcn_rcpf(mx);
    float s = a * a;
    float r = fmaf(fmaf(fmaf(fmaf(0.0208351f, s, -0.085133f), s, 0.180141f),
                        s, -0.3302995f), s, 0.999866f) * a;
    if (ay > ax) r = 1.5707963268f - r;
    if (x < 0.0f) r = 3.1415926536f - r;
    return (y < 0.0f) ? -r : r;
}

// ---------------- 16-point building blocks (row_fft path, unchanged) -------
__device__ __forceinline__ constexpr int ridx(int k) { return ((k & 3) << 2) | (k >> 2); }

__device__ __forceinline__ void fft16_ip(float2* d) {
    const float2 Wt1[4] = {{1.f, 0.f},
                           {0.92387953f, -0.38268343f},
                           {0.70710678f, -0.70710678f},
                           {0.38268343f, -0.92387953f}};
    const float2 Wt2[4] = {{1.f, 0.f},
                           {0.70710678f, -0.70710678f},
                           {0.f, -1.f},
                           {-0.70710678f, -0.70710678f}};
    const float2 Wt3[4] = {{1.f, 0.f},
                           {0.38268343f, -0.92387953f},
                           {-0.70710678f, -0.70710678f},
                           {-0.92387953f, 0.38268343f}};
#pragma unroll
    for (int t = 0; t < 4; ++t) {
        float2 x0 = d[t], x1 = d[t + 4], x2 = d[t + 8], x3 = d[t + 12];
        float2 a0 = cadd(x0, x2), a1 = csub(x0, x2), a2 = cadd(x1, x3), a3 = csub(x1, x3);
        d[t]      = cadd(a0, a2);
        d[t + 4]  = cmul(make_float2(a1.x + a3.y, a1.y - a3.x), Wt1[t]);
        d[t + 8]  = cmul(csub(a0, a2), Wt2[t]);
        d[t + 12] = cmul(make_float2(a1.x - a3.y, a1.y + a3.x), Wt3[t]);
    }
#pragma unroll
    for (int r = 0; r < 4; ++r) {
        float2 x0 = d[4 * r], x1 = d[4 * r + 1], x2 = d[4 * r + 2], x3 = d[4 * r + 3];
        float2 e0 = cadd(x0, x2), e1 = csub(x0, x2), e2 = cadd(x1, x3), e3 = csub(x1, x3);
        d[4 * r]     = cadd(e0, e2);
        d[4 * r + 1] = make_float2(e1.x + e3.y, e1.y - e3.x);
        d[4 * r + 2] = csub(e0, e2);
        d[4 * r + 3] = make_float2(e1.x - e3.y, e1.y + e3.x);
    }
}

__device__ __forceinline__ void twiddle_tree(float2 T, float2* Wt) {
    Wt[1] = T;
    Wt[2] = cmul(T, T);
    Wt[3] = cmul(Wt[2], T);
    Wt[4] = cmul(Wt[2], Wt[2]);
    Wt[5] = cmul(Wt[4], Wt[1]);
    Wt[6] = cmul(Wt[4], Wt[2]);
    Wt[7] = cmul(Wt[4], Wt[3]);
    Wt[8] = cmul(Wt[4], Wt[4]);
    Wt[9]  = cmul(Wt[8], Wt[1]);
    Wt[10] = cmul(Wt[8], Wt[2]);
    Wt[11] = cmul(Wt[8], Wt[3]);
    Wt[12] = cmul(Wt[8], Wt[4]);
    Wt[13] = cmul(Wt[8], Wt[5]);
    Wt[14] = cmul(Wt[8], Wt[6]);
    Wt[15] = cmul(Wt[8], Wt[7]);
}

// Wave-level 1024-pt FFT (row_fft_kernel only).
__device__ __forceinline__ void wave_fft1024(float2* v, float2* sb, int lane) {
    fft16_ip(v);
    float s, c;
    __sincosf(-TWO_PI_F * (float)lane * (1.0f / 1024.0f), &s, &c);
    float2 Wt[16];
    twiddle_tree(make_float2(c, s), Wt);
#pragma unroll
    for (int k2 = 1; k2 < 16; ++k2) v[ridx(k2)] = cmul(v[ridx(k2)], Wt[k2]);
    const int k2p = lane & 15, qp = lane >> 4;
#pragma unroll
    for (int k2 = 0; k2 < 16; ++k2) sb[(k2 << 6) | (lane ^ k2)] = v[ridx(k2)];
    LGKM_SYNC();
#pragma unroll
    for (int m = 0; m < 16; ++m) v[m] = sb[(k2p << 6) | ((4 * m + qp) ^ k2p)];
    LGKM_SYNC();
    fft16_ip(v);
    __sincosf(-TWO_PI_F * (float)qp * (1.0f / 64.0f), &s, &c);
    twiddle_tree(make_float2(c, s), Wt);
#pragma unroll
    for (int km = 1; km < 16; ++km) v[ridx(km)] = cmul(v[ridx(km)], Wt[km]);
    const bool hi2 = (lane & 32) != 0, hi1 = (lane & 16) != 0;
#pragma unroll
    for (int m = 0; m < 16; ++m) {
        float2 a = v[m];
        float2 o = make_float2(__shfl_xor(a.x, 32, 64), __shfl_xor(a.y, 32, 64));
        float2 s1 = hi2 ? csub(o, a) : cadd(a, o);
        if (hi2 && hi1) s1 = make_float2(s1.y, -s1.x);
        float2 o2 = make_float2(__shfl_xor(s1.x, 16, 64), __shfl_xor(s1.y, 16, 64));
        v[m] = hi1 ? csub(o2, s1) : cadd(s1, o2);
    }
}

// ---------------------------------------------------------------------------
// Kernel A: unchanged (round-2 structure).
// ---------------------------------------------------------------------------
__global__ __launch_bounds__(256, 4) void row_fft_kernel(const float* __restrict__ x,
                                                         float2* __restrict__ rf2) {
    __shared__ float2 buf[4][1024];
    const int t = threadIdx.x, w = t >> 6, lane = t & 63;
    const int b = blockIdx.x >> 7;
    const int h0 = (blockIdx.x & 127) * 8;
    const float* r0 = x + ((long long)b * HH + h0 + 2 * w) * (long long)WW;
    const float* r1 = r0 + WW;
    float2 v[16];
#pragma unroll
    for (int j = 0; j < 16; ++j) v[j] = make_float2(r0[lane + 64 * j], r1[lane + 64 * j]);
    float2* mybuf = &buf[w][0];
    wave_fft1024(v, mybuf, lane);
    const int kq = 2 * ((lane >> 4) & 1) + ((lane >> 5) & 1);
    const int kbase = (lane & 15) + 256 * kq;
#pragma unroll
    for (int m = 0; m < 16; ++m) mybuf[kbase + 16 * m] = v[ridx(m)];
    __syncthreads();
    for (int idx = t; idx < 513 * 8; idx += 256) {
        int k = idx >> 3, j = idx & 7, p = j >> 1, which = j & 1;
        float2 zk = buf[p][k];
        float2 zn = buf[p][(1024 - k) & 1023];
        float2 val = which ? make_float2(0.5f * (zk.y + zn.y), 0.5f * (zn.x - zk.x))
                           : make_float2(0.5f * (zk.x + zn.x), 0.5f * (zk.y - zn.y));
        rf2[((long long)b * WR + k) * 1024 + h0 + j] = val;
    }
}

// ---------------------------------------------------------------------------
// Kernel B: FOUR-STEP col FFT (1024 = 32x32). R0-R5 established the
// bottleneck is the 16x64 factorization's dependency structure: ~96
// latency-chained DS ops/row (64 shfl = ds_bpermute in 16 serial 2-stage
// chains + 2-fence transpose); VALU-saturation bound = 31 us but measured
// 181 us at VALUBusy 17%, invariant to all scheduling. Four-step removes
// ALL cross-lane butterflies: each lane owns one n1-column (lane&31) of one
// row (lane>>5; 2 rows/wave), does an in-register FFT32 (pure VALU), the
// W1024^{n1*k1} twiddle, ONE padded-LDS transpose (32 coalesced writes ->
// 1 fence -> 32 offset-folded reads, stride-33 = conflict-free), a second
// in-register FFT32, and perfectly coalesced phase stores (k = K1 + 32*k2,
// lanes = K1 consecutive). DS ops/row: 32, dependency depth 1.
// ---------------------------------------------------------------------------
__device__ __forceinline__ constexpr int brev5(int k) {
    return ((k & 1) << 4) | ((k & 2) << 2) | (k & 4) | ((k & 8) >> 2) | ((k & 16) >> 4);
}

// In-place radix-2 DIF FFT-32. Natural-order input d[0..31];
// output bit-reversed: d[brev5(k)] = X[k]. All twiddles compile-time.
__device__ __forceinline__ void fft32_dif(float2* d) {
    const float2 TW[16] = {
        {1.f, 0.f},
        {0.98078528f, -0.19509032f},
        {0.92387953f, -0.38268343f},
        {0.83146961f, -0.55557023f},
        {0.70710678f, -0.70710678f},
        {0.55557023f, -0.83146961f},
        {0.38268343f, -0.92387953f},
        {0.19509032f, -0.98078528f},
        {0.f, -1.f},
        {-0.19509032f, -0.98078528f},
        {-0.38268343f, -0.92387953f},
        {-0.55557023f, -0.83146961f},
        {-0.70710678f, -0.70710678f},
        {-0.83146961f, -0.55557023f},
        {-0.92387953f, -0.38268343f},
        {-0.98078528f, -0.19509032f}};
#pragma unroll
    for (int s = 0; s < 5; ++s) {
        const int h = 16 >> s;
#pragma unroll
        for (int b = 0; b < 32; b += 2 * h) {
#pragma unroll
            for (int j = 0; j < h; ++j) {
                float2 a = d[b + j], c = d[b + j + h];
                d[b + j]     = cadd(a, c);
                d[b + j + h] = cmul(csub(a, c), TW[j << s]);
            }
        }
    }
}

__global__ __launch_bounds__(64, 4) void col_fft_kernel(float2* __restrict__ rf2,
                                                        float* __restrict__ magmax) {
    __shared__ float2 sb[2 * 1056];        // 2 rows x (32*33) padded, 16.9 KB
    const int lane = threadIdx.x;          // 64-thread block = 1 wave
    const int n1 = lane & 31, row = lane >> 5;
    const long long fbase = (long long)blockIdx.x * 2;
    const long long fid = fbase + row;
    const float2* src = rf2 + fbase * 1024;

    // Coalesced loads: instruction j -> lanes read consecutive addresses.
    float2 d[32];
#pragma unroll
    for (int j = 0; j < 32; ++j) d[j] = src[row * 1024 + n1 + 32 * j];

    // Pass 1: FFT32 over n2 (in-lane).  d[brev5(k1)] = A[n1][k1]
    fft32_dif(d);

    // Twiddle A[n1][k1] *= W1024^{n1*k1} (per-lane serial power chain,
    // chain latency hidden under the 10-instr/iter issue stream).
    float s0, c0;
    __sincosf(-TWO_PI_F * (float)n1 * (1.0f / 1024.0f), &s0, &c0);
    const float2 Tn = make_float2(c0, s0);
    float2 ww = Tn;
#pragma unroll
    for (int k1 = 1; k1 < 32; ++k1) {
        d[brev5(k1)] = cmul(d[brev5(k1)], ww);
        if (k1 < 31) ww = cmul(ww, Tn);
    }

    // Transpose via padded LDS (stride 33 float2 = conflict-free both sides).
    // Write: A[n1][k1] at [33*k1 + n1] (lanes n1 consecutive).
    float2* myLDS = sb + row * 1056;
#pragma unroll
    for (int k1 = 0; k1 < 32; ++k1) myLDS[33 * k1 + n1] = d[brev5(k1)];
    LGKM_SYNC();
    // Read: lane K1(=n1 var) gets A[j][K1] at [33*K1 + j] — offsets fold
    // into ds_read immediates. Compiler inserts the read->use wait.
#pragma unroll
    for (int j = 0; j < 32; ++j) d[j] = myLDS[33 * n1 + j];

    // Pass 2: FFT32 over n1 (in-lane).  d[brev5(k2)] = X[K1 + 32*k2]
    fft32_dif(d);

    // Epilogue: phase + magnitude. Stores coalesced (lanes = K1 consecutive).
    float* pu = (float*)(rf2 + fid * 1024);
    float mmax = 0.0f;
#pragma unroll
    for (int k2 = 0; k2 < 32; ++k2) {
        float2 z = d[brev5(k2)];
        mmax = fmaxf(mmax, __builtin_amdgcn_sqrtf(z.x * z.x + z.y * z.y));
        float ph = fast_atan2f(z.y, z.x);
        pu[32 * k2 + n1] = (ph < 0.0f) ? ph + TWO_PI_F : ph;
    }
    // Per-row (half-wave) max reduce, then one atomic per row.
#pragma unroll
    for (int off = 16; off; off >>= 1) mmax = fmaxf(mmax, __shfl_xor(mmax, off, 64));
    if (n1 == 0) atomicMax((int*)(magmax + (int)(fid / WR)), __float_as_int(mmax));
}

// ---------------------------------------------------------------------------
// Kernel C: gradients + 55 Zernike moments, float4-vectorized (unchanged R5).
// ---------------------------------------------------------------------------
#define WRED(var, idx)                                                     \
    {                                                                      \
        float r_ = var;                                                    \
        _Pragma("unroll")                                                  \
        for (int off_ = 32; off_; off_ >>= 1) r_ += __shfl_down(r_, off_); \
        if (lane == 0) red[wv * 64 + (idx)] = r_;                          \
    }

#define ZPIX(VV, YVV)                                                          \
    {                                                                          \
        const float yv_ = (YVV);                                               \
        const float r2_ = xv2 + yv_ * yv_;                                     \
        if (r2_ <= 1.0f) {                                                     \
            cnt += 1.0f;                                                       \
            const float rho = sqrtf(r2_);                                      \
            const float inv = rsqrtf(r2_);                                     \
            const float c1 = xv * inv;                                         \
            const float s1 = yv_ * inv;                                        \
            const float c2 = 2.f * c1 * c1 - 1.f;                              \
            const float c3 = 2.f * c1 * c2 - c1;                               \
            const float c4 = 2.f * c1 * c3 - c2;                               \
            const float c5 = 2.f * c1 * c4 - c3;                               \
            const float c6 = 2.f * c1 * c5 - c4;                               \
            const float c7 = 2.f * c1 * c6 - c5;                               \
            const float c8 = 2.f * c1 * c7 - c6;                               \
            const float c9 = 2.f * c1 * c8 - c7;                               \
            const float s2 = 2.f * c1 * s1;                                    \
            const float s3 = 2.f * c1 * s2 - s1;                               \
            const float s4 = 2.f * c1 * s3 - s2;                               \
            const float s5 = 2.f * c1 * s4 - s3;                               \
            const float s6 = 2.f * c1 * s5 - s4;                               \
            const float s7 = 2.f * c1 * s6 - s5;                               \
            const float s8 = 2.f * c1 * s7 - s6;                               \
            const float s9 = 2.f * c1 * s8 - s7;                               \
            const float w0 = (VV), w1 = w0 * rho, w2 = w1 * rho, w3 = w2 * rho,\
                        w4 = w3 * rho, w5 = w4 * rho, w6 = w5 * rho,           \
                        w7 = w6 * rho, w8 = w7 * rho, w9 = w8 * rho;           \
            a00 += w0;                                                         \
            a11 += w1 * c1;                                                    \
            a20 += w2;      a22 += w2 * c2;                                    \
            a31 += w3 * c1; a33 += w3 * c3;                                    \
            a40 += w4;      a42 += w4 * c2; a44 += w4 * c4;                    \
            a51 += w5 * c1; a53 += w5 * c3; a55 += w5 * c5;                    \
            a60 += w6;      a62 += w6 * c2; a64 += w6 * c4; a66 += w6 * c6;    \
            a71 += w7 * c1; a73 += w7 * c3; a75 += w7 * c5; a77 += w7 * c7;    \
            a80 += w8;      a82 += w8 * c2; a84 += w8 * c4; a86 += w8 * c6;    \
            a88 += w8 * c8;                                                    \
            a91 += w9 * c1; a93 += w9 * c3; a95 += w9 * c5; a97 += w9 * c7;    \
            a99 += w9 * c9;                                                    \
            b11 += w1 * s1;                                                    \
            b22 += w2 * s2;                                                    \
            b31 += w3 * s1; b33 += w3 * s3;                                    \
            b42 += w4 * s2; b44 += w4 * s4;                                    \
            b51 += w5 * s1; b53 += w5 * s3; b55 += w5 * s5;                    \
            b62 += w6 * s2; b64 += w6 * s4; b66 += w6 * s6;                    \
            b71 += w7 * s1; b73 += w7 * s3; b75 += w7 * s5; b77 += w7 * s7;    \
            b82 += w8 * s2; b84 += w8 * s4; b86 += w8 * s6; b88 += w8 * s8;    \
            b91 += w9 * s1; b93 += w9 * s3; b95 += w9 * s5; b97 += w9 * s7;    \
            b99 += w9 * s9;                                                    \
        }                                                                      \
    }

__global__ __launch_bounds__(256, 2) void stats_kernel(float* __restrict__ pu) {
    __shared__ float red[4 * 64];
    const int b = blockIdx.y;
    const int k0 = blockIdx.x * 9;
    const float* base = pu + (long long)b * WR * 2048;
    float a00 = 0.f, a11 = 0.f, a20 = 0.f, a22 = 0.f, a31 = 0.f, a33 = 0.f,
          a40 = 0.f, a42 = 0.f, a44 = 0.f, a51 = 0.f, a53 = 0.f, a55 = 0.f,
          a60 = 0.f, a62 = 0.f, a64 = 0.f, a66 = 0.f, a71 = 0.f, a73 = 0.f,
          a75 = 0.f, a77 = 0.f, a80 = 0.f, a82 = 0.f, a84 = 0.f, a86 = 0.f,
          a88 = 0.f, a91 = 0.f, a93 = 0.f, a95 = 0.f, a97 = 0.f, a99 = 0.f;
    float b11 = 0.f, b22 = 0.f, b31 = 0.f, b33 = 0.f, b42 = 0.f, b44 = 0.f,
          b51 = 0.f, b53 = 0.f, b55 = 0.f, b62 = 0.f, b64 = 0.f, b66 = 0.f,
          b71 = 0.f, b73 = 0.f, b75 = 0.f, b77 = 0.f, b82 = 0.f, b84 = 0.f,
          b86 = 0.f, b88 = 0.f, b91 = 0.f, b93 = 0.f, b95 = 0.f, b97 = 0.f,
          b99 = 0.f;
    float sgx = 0.f, sgx2 = 0.f, sgy = 0.f, sgy2 = 0.f, cnt = 0.f;

    const int h4 = threadIdx.x * 4;
    const float yv0 = -1.0f + (2.0f / 1023.0f) * (float)h4;
    const float ystep = 2.0f / 1023.0f;

    for (int kk = 0; kk < 9; ++kk) {
        const int k = k0 + kk;
        const float* rowc = base + (long long)k * 2048;
        const float xv = -1.0f + (1.0f / 256.0f) * (float)k;
        const float xv2 = xv * xv;

        const float4 vc = *reinterpret_cast<const float4*>(rowc + h4);
        float4 gx4;
        if (k == 0) {
            const float4 vp = *reinterpret_cast<const float4*>(rowc + 2048 + h4);
            gx4 = make_float4(vp.x - vc.x, vp.y - vc.y, vp.z - vc.z, vp.w - vc.w);
        } else if (k == WR - 1) {
            const float4 vm = *reinterpret_cast<const float4*>(rowc - 2048 + h4);
            gx4 = make_float4(vc.x - vm.x, vc.y - vm.y, vc.z - vm.z, vc.w - vm.w);
        } else {
            const float4 vm = *reinterpret_cast<const float4*>(rowc - 2048 + h4);
            const float4 vp = *reinterpret_cast<const float4*>(rowc + 2048 + h4);
            gx4 = make_float4(0.5f * (vp.x - vm.x), 0.5f * (vp.y - vm.y),
                              0.5f * (vp.z - vm.z), 0.5f * (vp.w - vm.w));
        }
        const float left  = rowc[(h4 > 0) ? h4 - 1 : 0];
        const float right = rowc[(h4 < 1020) ? h4 + 4 : 1023];
        const float gy0 = (h4 == 0)    ? vc.y - vc.x : 0.5f * (vc.y - left);
        const float gy1 = 0.5f * (vc.z - vc.x);
        const float gy2 = 0.5f * (vc.w - vc.y);
        const float gy3 = (h4 == 1020) ? vc.w - vc.z : 0.5f * (right - vc.z);

        sgx  += gx4.x + gx4.y + gx4.z + gx4.w;
        sgx2 += gx4.x * gx4.x + gx4.y * gx4.y + gx4.z * gx4.z + gx4.w * gx4.w;
        sgy  += gy0 + gy1 + gy2 + gy3;
        sgy2 += gy0 * gy0 + gy1 * gy1 + gy2 * gy2 + gy3 * gy3;

        ZPIX(vc.x, yv0);
        ZPIX(vc.y, yv0 + ystep);
        ZPIX(vc.z, yv0 + 2.0f * ystep);
        ZPIX(vc.w, yv0 + 3.0f * ystep);
    }

    const int wv = threadIdx.x >> 6, lane = threadIdx.x & 63;
    WRED(a00, 0);  WRED(a11, 1);  WRED(a20, 2);  WRED(a22, 3);  WRED(a31, 4);
    WRED(a33, 5);  WRED(a40, 6);  WRED(a42, 7);  WRED(a44, 8);  WRED(a51, 9);
    WRED(a53, 10); WRED(a55, 11); WRED(a60, 12); WRED(a62, 13); WRED(a64, 14);
    WRED(a66, 15); WRED(a71, 16); WRED(a73, 17); WRED(a75, 18); WRED(a77, 19);
    WRED(a80, 20); WRED(a82, 21); WRED(a84, 22); WRED(a86, 23); WRED(a88, 24);
    WRED(a91, 25); WRED(a93, 26); WRED(a95, 27); WRED(a97, 28); WRED(a99, 29);
    WRED(b11, 30); WRED(b22, 31); WRED(b31, 32); WRED(b33, 33); WRED(b42, 34);
    WRED(b44, 35); WRED(b51, 36); WRED(b53, 37); WRED(b55, 38); WRED(b62, 39);
    WRED(b64, 40); WRED(b66, 41); WRED(b71, 42); WRED(b73, 43); WRED(b75, 44);
    WRED(b77, 45); WRED(b82, 46); WRED(b84, 47); WRED(b86, 48); WRED(b88, 49);
    WRED(b91, 50); WRED(b93, 51); WRED(b95, 52); WRED(b97, 53); WRED(b99, 54);
    WRED(sgx, 55); WRED(sgx2, 56); WRED(sgy, 57); WRED(sgy2, 58); WRED(cnt, 59);
    __syncthreads();
    const int t = threadIdx.x;
    if (t < 60) {
        float s = red[t] + red[64 + t] + red[128 + t] + red[192 + t];
        pu[((long long)(b * 57 + blockIdx.x)) * 2048 + 1024 + t] = s;
    }
}

// ---------------------------------------------------------------------------
// Kernel D: unchanged.
// ---------------------------------------------------------------------------
__device__ int moment_index(int p, int a, int is_cos) {
    int ai = 0;
    for (int pp = 0; pp < 10; ++pp)
        for (int aa = (pp & 1); aa <= pp; aa += 2) {
            if (is_cos && pp == p && aa == a) return ai;
            ++ai;
        }
    for (int pp = 1; pp < 10; ++pp)
        for (int aa = ((pp & 1) ? 1 : 2); aa <= pp; aa += 2) {
            if (!is_cos && pp == p && aa == a) return ai;
            ++ai;
        }
    return 0;
}

__device__ float factf(int n) {
    float f = 1.0f;
    for (int i = 2; i <= n; ++i) f *= (float)i;
    return f;
}

__global__ void finalize_kernel(const float* __restrict__ pu,
                                const float* __restrict__ magmax,
                                float* __restrict__ out) {
    __shared__ float abf[64];
    const int b = blockIdx.x;
    const int j = threadIdx.x;
    if (j < 60) {
        float s = 0.0f;
        for (int i = 0; i < 57; ++i)
            s += pu[((long long)(b * 57 + i)) * 2048 + 1024 + j];
        abf[j] = s;
    }
    __syncthreads();
    if (j >= 60) return;
    const float NF = (float)NPIX;
    float val;
    if (j < 55) {
        int tt = j, n = 0;
        while (tt >= n + 1) { tt -= (n + 1); ++n; }
        int m = -n + 2 * tt;
        int am = m < 0 ? -m : m;
        float s = 0.0f;
        for (int k = 0; k <= (n - am) / 2; ++k) {
            float c = factf(n - k) /
                      (factf(k) * factf((n + am) / 2 - k) * factf((n - am) / 2 - k));
            if (k & 1) c = -c;
            int p = n - 2 * k;
            s += c * abf[moment_index(p, am, m >= 0 ? 1 : 0)];
        }
        val = s / abf[59];
    } else if (j == 55) {
        val = abf[55] / NF;
    } else if (j == 56) {
        val = abf[57] / NF;
    } else if (j == 57) {
        float sum = abf[55], sq = abf[56];
        val = sqrtf(fmaxf(0.0f, (sq - sum * sum / NF) / (NF - 1.0f)));
    } else if (j == 58) {
        float sum = abf[57], sq = abf[58];
        val = sqrtf(fmaxf(0.0f, (sq - sum * sum / NF) / (NF - 1.0f)));
    } else {
        val = magmax[b];
    }
    out[b * 60 + j] = val;
}

// ---------------------------------------------------------------------------
extern "C" void kernel_launch(void* const* d_in, const int* in_sizes, int n_in,
                              void* d_out, int out_size, void* d_ws, size_t ws_size,
                              hipStream_t stream) {
    (void)in_sizes; (void)n_in; (void)out_size; (void)ws_size;
    const float* x = (const float*)d_in[0];
    float* out = (float*)d_out;

    float* magmax = (float*)d_ws;                  // 32 floats (atomicMax target)
    float2* rf2 = (float2*)((char*)d_ws + 16384);  // [B][WR][H] float2 = 134.5 MB

    hipMemsetAsync(d_ws, 0, 16384, stream);
    row_fft_kernel<<<BATCH * 128, 256, 0, stream>>>(x, rf2);
    // 16416 rows / 2 rows-per-wave = 8208 one-wave blocks
    col_fft_kernel<<<8208, 64, 0, stream>>>(rf2, magmax);
    dim3 gridC(57, BATCH);
    stats_kernel<<<gridC, 256, 0, stream>>>((float*)rf2);
    finalize_kernel<<<BATCH, 64, 0, stream>>>((const float*)rf2, magmax, out);
}

// Round 8
// 442.613 us; speedup vs baseline: 1.1863x; 1.1654x over previous
//
#include <hip/hip_runtime.h>
#include <math.h>

#define BATCH 32
#define HH 1024
#define WW 1024
#define WR 513
#define NPIX (HH * WR)
#define TWO_PI_F 6.28318530717958647692f

// Same-wave LDS fence: wait for this wave's own LDS ops.
#define LGKM_SYNC() __asm__ __volatile__("s_waitcnt lgkmcnt(0)" ::: "memory")

__device__ __forceinline__ float2 cadd(float2 a, float2 b) { return make_float2(a.x + b.x, a.y + b.y); }
__device__ __forceinline__ float2 csub(float2 a, float2 b) { return make_float2(a.x - b.x, a.y - b.y); }
__device__ __forceinline__ float2 cmul(float2 a, float2 b) {
    return make_float2(a.x * b.x - a.y * b.y, a.x * b.y + a.y * b.x);
}

// atan2 via odd minimax poly on [0,1] (max err ~1e-5 rad) + quadrant fixup.
__device__ __forceinline__ float fast_atan2f(float y, float x) {
    float ax = __builtin_fabsf(x), ay = __builtin_fabsf(y);
    float mx = fmaxf(ax, ay), mn = fminf(ax, ay);
    float a = mn * __builtin_amdgcn_rcpf(mx);
    float s = a * a;
    float r = fmaf(fmaf(fmaf(fmaf(0.0208351f, s, -0.085133f), s, 0.180141f),
                        s, -0.3302995f), s, 0.999866f) * a;
    if (ay > ax) r = 1.5707963268f - r;
    if (x < 0.0f) r = 3.1415926536f - r;
    return (y < 0.0f) ? -r : r;
}

// ---------------- 16-point building blocks (row_fft path, unchanged) -------
__device__ __forceinline__ constexpr int ridx(int k) { return ((k & 3) << 2) | (k >> 2); }

__device__ __forceinline__ void fft16_ip(float2* d) {
    const float2 Wt1[4] = {{1.f, 0.f},
                           {0.92387953f, -0.38268343f},
                           {0.70710678f, -0.70710678f},
                           {0.38268343f, -0.92387953f}};
    const float2 Wt2[4] = {{1.f, 0.f},
                           {0.70710678f, -0.70710678f},
                           {0.f, -1.f},
                           {-0.70710678f, -0.70710678f}};
    const float2 Wt3[4] = {{1.f, 0.f},
                           {0.38268343f, -0.92387953f},
                           {-0.70710678f, -0.70710678f},
                           {-0.92387953f, 0.38268343f}};
#pragma unroll
    for (int t = 0; t < 4; ++t) {
        float2 x0 = d[t], x1 = d[t + 4], x2 = d[t + 8], x3 = d[t + 12];
        float2 a0 = cadd(x0, x2), a1 = csub(x0, x2), a2 = cadd(x1, x3), a3 = csub(x1, x3);
        d[t]      = cadd(a0, a2);
        d[t + 4]  = cmul(make_float2(a1.x + a3.y, a1.y - a3.x), Wt1[t]);
        d[t + 8]  = cmul(csub(a0, a2), Wt2[t]);
        d[t + 12] = cmul(make_float2(a1.x - a3.y, a1.y + a3.x), Wt3[t]);
    }
#pragma unroll
    for (int r = 0; r < 4; ++r) {
        float2 x0 = d[4 * r], x1 = d[4 * r + 1], x2 = d[4 * r + 2], x3 = d[4 * r + 3];
        float2 e0 = cadd(x0, x2), e1 = csub(x0, x2), e2 = cadd(x1, x3), e3 = csub(x1, x3);
        d[4 * r]     = cadd(e0, e2);
        d[4 * r + 1] = make_float2(e1.x + e3.y, e1.y - e3.x);
        d[4 * r + 2] = csub(e0, e2);
        d[4 * r + 3] = make_float2(e1.x - e3.y, e1.y + e3.x);
    }
}

__device__ __forceinline__ void twiddle_tree(float2 T, float2* Wt) {
    Wt[1] = T;
    Wt[2] = cmul(T, T);
    Wt[3] = cmul(Wt[2], T);
    Wt[4] = cmul(Wt[2], Wt[2]);
    Wt[5] = cmul(Wt[4], Wt[1]);
    Wt[6] = cmul(Wt[4], Wt[2]);
    Wt[7] = cmul(Wt[4], Wt[3]);
    Wt[8] = cmul(Wt[4], Wt[4]);
    Wt[9]  = cmul(Wt[8], Wt[1]);
    Wt[10] = cmul(Wt[8], Wt[2]);
    Wt[11] = cmul(Wt[8], Wt[3]);
    Wt[12] = cmul(Wt[8], Wt[4]);
    Wt[13] = cmul(Wt[8], Wt[5]);
    Wt[14] = cmul(Wt[8], Wt[6]);
    Wt[15] = cmul(Wt[8], Wt[7]);
}

// Wave-level 1024-pt FFT (row_fft_kernel only).
__device__ __forceinline__ void wave_fft1024(float2* v, float2* sb, int lane) {
    fft16_ip(v);
    float s, c;
    __sincosf(-TWO_PI_F * (float)lane * (1.0f / 1024.0f), &s, &c);
    float2 Wt[16];
    twiddle_tree(make_float2(c, s), Wt);
#pragma unroll
    for (int k2 = 1; k2 < 16; ++k2) v[ridx(k2)] = cmul(v[ridx(k2)], Wt[k2]);
    const int k2p = lane & 15, qp = lane >> 4;
#pragma unroll
    for (int k2 = 0; k2 < 16; ++k2) sb[(k2 << 6) | (lane ^ k2)] = v[ridx(k2)];
    LGKM_SYNC();
#pragma unroll
    for (int m = 0; m < 16; ++m) v[m] = sb[(k2p << 6) | ((4 * m + qp) ^ k2p)];
    LGKM_SYNC();
    fft16_ip(v);
    __sincosf(-TWO_PI_F * (float)qp * (1.0f / 64.0f), &s, &c);
    twiddle_tree(make_float2(c, s), Wt);
#pragma unroll
    for (int km = 1; km < 16; ++km) v[ridx(km)] = cmul(v[ridx(km)], Wt[km]);
    const bool hi2 = (lane & 32) != 0, hi1 = (lane & 16) != 0;
#pragma unroll
    for (int m = 0; m < 16; ++m) {
        float2 a = v[m];
        float2 o = make_float2(__shfl_xor(a.x, 32, 64), __shfl_xor(a.y, 32, 64));
        float2 s1 = hi2 ? csub(o, a) : cadd(a, o);
        if (hi2 && hi1) s1 = make_float2(s1.y, -s1.x);
        float2 o2 = make_float2(__shfl_xor(s1.x, 16, 64), __shfl_xor(s1.y, 16, 64));
        v[m] = hi1 ? csub(o2, s1) : cadd(s1, o2);
    }
}

// ---------------------------------------------------------------------------
// Kernel A: unchanged.
// ---------------------------------------------------------------------------
__global__ __launch_bounds__(256, 4) void row_fft_kernel(const float* __restrict__ x,
                                                         float2* __restrict__ rf2) {
    __shared__ float2 buf[4][1024];
    const int t = threadIdx.x, w = t >> 6, lane = t & 63;
    const int b = blockIdx.x >> 7;
    const int h0 = (blockIdx.x & 127) * 8;
    const float* r0 = x + ((long long)b * HH + h0 + 2 * w) * (long long)WW;
    const float* r1 = r0 + WW;
    float2 v[16];
#pragma unroll
    for (int j = 0; j < 16; ++j) v[j] = make_float2(r0[lane + 64 * j], r1[lane + 64 * j]);
    float2* mybuf = &buf[w][0];
    wave_fft1024(v, mybuf, lane);
    const int kq = 2 * ((lane >> 4) & 1) + ((lane >> 5) & 1);
    const int kbase = (lane & 15) + 256 * kq;
#pragma unroll
    for (int m = 0; m < 16; ++m) mybuf[kbase + 16 * m] = v[ridx(m)];
    __syncthreads();
    for (int idx = t; idx < 513 * 8; idx += 256) {
        int k = idx >> 3, j = idx & 7, p = j >> 1, which = j & 1;
        float2 zk = buf[p][k];
        float2 zn = buf[p][(1024 - k) & 1023];
        float2 val = which ? make_float2(0.5f * (zk.y + zn.y), 0.5f * (zn.x - zk.x))
                           : make_float2(0.5f * (zk.x + zn.x), 0.5f * (zk.y - zn.y));
        rf2[((long long)b * WR + k) * 1024 + h0 + j] = val;
    }
}

// ------------------------- 32-point FFT (four-step) ------------------------
__device__ __forceinline__ constexpr int brev5(int k) {
    return ((k & 1) << 4) | ((k & 2) << 2) | (k & 4) | ((k & 8) >> 2) | ((k & 16) >> 4);
}

__device__ __forceinline__ void fft32_dif(float2* d) {
    const float2 TW[16] = {
        {1.f, 0.f},
        {0.98078528f, -0.19509032f},
        {0.92387953f, -0.38268343f},
        {0.83146961f, -0.55557023f},
        {0.70710678f, -0.70710678f},
        {0.55557023f, -0.83146961f},
        {0.38268343f, -0.92387953f},
        {0.19509032f, -0.98078528f},
        {0.f, -1.f},
        {-0.19509032f, -0.98078528f},
        {-0.38268343f, -0.92387953f},
        {-0.55557023f, -0.83146961f},
        {-0.70710678f, -0.70710678f},
        {-0.83146961f, -0.55557023f},
        {-0.92387953f, -0.38268343f},
        {-0.98078528f, -0.19509032f}};
#pragma unroll
    for (int s = 0; s < 5; ++s) {
        const int h = 16 >> s;
#pragma unroll
        for (int b = 0; b < 32; b += 2 * h) {
#pragma unroll
            for (int j = 0; j < h; ++j) {
                float2 a = d[b + j], c = d[b + j + h];
                d[b + j]     = cadd(a, c);
                d[b + j + h] = cmul(csub(a, c), TW[j << s]);
            }
        }
    }
}

// Masked Zernike accumulation for one pixel (uses enclosing-scope names).
#define ZPIX(VV, YVV)                                                          \
    {                                                                          \
        const float yv_ = (YVV);                                               \
        const float r2_ = xv2 + yv_ * yv_;                                     \
        if (r2_ <= 1.0f) {                                                     \
            cnt += 1.0f;                                                       \
            const float rho = sqrtf(r2_);                                      \
            const float inv = rsqrtf(r2_);                                     \
            const float c1 = xv * inv;                                         \
            const float s1 = yv_ * inv;                                        \
            const float c2 = 2.f * c1 * c1 - 1.f;                              \
            const float c3 = 2.f * c1 * c2 - c1;                               \
            const float c4 = 2.f * c1 * c3 - c2;                               \
            const float c5 = 2.f * c1 * c4 - c3;                               \
            const float c6 = 2.f * c1 * c5 - c4;                               \
            const float c7 = 2.f * c1 * c6 - c5;                               \
            const float c8 = 2.f * c1 * c7 - c6;                               \
            const float c9 = 2.f * c1 * c8 - c7;                               \
            const float s2 = 2.f * c1 * s1;                                    \
            const float s3 = 2.f * c1 * s2 - s1;                               \
            const float s4 = 2.f * c1 * s3 - s2;                               \
            const float s5 = 2.f * c1 * s4 - s3;                               \
            const float s6 = 2.f * c1 * s5 - s4;                               \
            const float s7 = 2.f * c1 * s6 - s5;                               \
            const float s8 = 2.f * c1 * s7 - s6;                               \
            const float s9 = 2.f * c1 * s8 - s7;                               \
            const float w0 = (VV), w1 = w0 * rho, w2 = w1 * rho, w3 = w2 * rho,\
                        w4 = w3 * rho, w5 = w4 * rho, w6 = w5 * rho,           \
                        w7 = w6 * rho, w8 = w7 * rho, w9 = w8 * rho;           \
            a00 += w0;                                                         \
            a11 += w1 * c1;                                                    \
            a20 += w2;      a22 += w2 * c2;                                    \
            a31 += w3 * c1; a33 += w3 * c3;                                    \
            a40 += w4;      a42 += w4 * c2; a44 += w4 * c4;                    \
            a51 += w5 * c1; a53 += w5 * c3; a55 += w5 * c5;                    \
            a60 += w6;      a62 += w6 * c2; a64 += w6 * c4; a66 += w6 * c6;    \
            a71 += w7 * c1; a73 += w7 * c3; a75 += w7 * c5; a77 += w7 * c7;    \
            a80 += w8;      a82 += w8 * c2; a84 += w8 * c4; a86 += w8 * c6;    \
            a88 += w8 * c8;                                                    \
            a91 += w9 * c1; a93 += w9 * c3; a95 += w9 * c5; a97 += w9 * c7;    \
            a99 += w9 * c9;                                                    \
            b11 += w1 * s1;                                                    \
            b22 += w2 * s2;                                                    \
            b31 += w3 * s1; b33 += w3 * s3;                                    \
            b42 += w4 * s2; b44 += w4 * s4;                                    \
            b51 += w5 * s1; b53 += w5 * s3; b55 += w5 * s5;                    \
            b62 += w6 * s2; b64 += w6 * s4; b66 += w6 * s6;                    \
            b71 += w7 * s1; b73 += w7 * s3; b75 += w7 * s5; b77 += w7 * s7;    \
            b82 += w8 * s2; b84 += w8 * s4; b86 += w8 * s6; b88 += w8 * s8;    \
            b91 += w9 * s1; b93 += w9 * s3; b95 += w9 * s5; b97 += w9 * s7;    \
            b99 += w9 * s9;                                                    \
        }                                                                      \
    }

#define WRED(var, idx)                                                     \
    {                                                                      \
        float r_ = var;                                                    \
        _Pragma("unroll")                                                  \
        for (int off_ = 32; off_; off_ >>= 1) r_ += __shfl_down(r_, off_); \
        if (lane == 0) red[w * 64 + (idx)] = r_;                           \
    }

// ---------------------------------------------------------------------------
// Kernel B (FUSED col FFT + stats). Theory (R0-R6): all big kernels sit at a
// ~1.2 TB/s LLC-streaming ceiling (rf2=134.5MB >> 32MB L2); col_fft time was
// invariant to algorithm/occupancy/scheduling because it's traffic-bound.
// So: cut traffic. Each block (4 waves) computes 8 column FFTs = 6 useful
// rows [k0..k0+5] + 2 halo (clamped), keeps phases in LDS, computes gx/gy,
// all 55 Zernike moments, cnt, mag-max directly -> ONE 60-float partial.
// Removes the 67MB phase write AND the stats kernel's ~200MB re-read.
// LDS hardened to EXACTLY 64KB (R7's 68.6KB may have exceeded the static
// limit -> container failure): XOR-swizzled transpose (addr=row*32+(col^row),
// same bank profile as the proven 33-pad layout: 2 lanes/bank-pair per
// half-wave both sides) + red[] overlaid in slot 0's dead scratch space.
// Partial target = rf2 row (b, k0+2): provably outside every block's read
// set (6bx'+2 == 6bx+d, d in [-1,6] => bx'==bx only), so no hazard.
// ---------------------------------------------------------------------------
__global__ __launch_bounds__(256, 2) void fused_col_stats_kernel(float2* __restrict__ rf2,
                                                                 float* __restrict__ magmax) {
    __shared__ float2 sb[8][1024];      // 64 KB exactly — static-LDS-limit safe
    float* red = (float*)&sb[0][512];   // 256 floats overlaid in dead scratch
    const int tid = threadIdx.x, w = tid >> 6, lane = tid & 63;
    const int n1 = lane & 31, s = lane >> 5;
    const int slot = 2 * w + s;                     // 0..7 = rows k0-1 .. k0+6
    const int bx = blockIdx.x, b = blockIdx.y;
    const int k0 = bx * 6;
    int kf = k0 - 1 + slot;
    kf = kf < 0 ? 0 : (kf > WR - 1 ? WR - 1 : kf);  // clamped halo (dupes unused)
    const float2* src = rf2 + ((long long)b * WR + kf) * 1024;

    // ---- four-step 1024-pt FFT over this slot's row (R6 structure) ----
    float2 d[32];
#pragma unroll
    for (int j = 0; j < 32; ++j) d[j] = src[n1 + 32 * j];
    fft32_dif(d);                                   // d[brev5(k1)] = A[n1][k1]
    float s0, c0;
    __sincosf(-TWO_PI_F * (float)n1 * (1.0f / 1024.0f), &s0, &c0);
    const float2 Tn = make_float2(c0, s0);
    float2 ww = Tn;
#pragma unroll
    for (int k1 = 1; k1 < 32; ++k1) {
        d[brev5(k1)] = cmul(d[brev5(k1)], ww);
        if (k1 < 31) ww = cmul(ww, Tn);
    }
    // XOR-swizzled transpose: logical (row,col) at physical row*32 + (col^row).
    float2* myLDS = &sb[slot][0];
#pragma unroll
    for (int k1 = 0; k1 < 32; ++k1) myLDS[(k1 << 5) | (n1 ^ k1)] = d[brev5(k1)];
    LGKM_SYNC();
#pragma unroll
    for (int j = 0; j < 32; ++j) d[j] = myLDS[(n1 << 5) | (j ^ n1)];
    fft32_dif(d);                                   // d[brev5(k2)] = X[n1 + 32*k2]

    // ---- epilogue: phase -> LDS (repurpose own scratch region), mag-max ----
    float* pul_own = (float*)&sb[slot][0];          // DS in-order: reads above done
    float mmax = 0.0f;
#pragma unroll
    for (int k2 = 0; k2 < 32; ++k2) {
        float2 z = d[brev5(k2)];
        mmax = fmaxf(mmax, __builtin_amdgcn_sqrtf(z.x * z.x + z.y * z.y));
        float ph = fast_atan2f(z.y, z.x);
        pul_own[32 * k2 + n1] = (ph < 0.0f) ? ph + TWO_PI_F : ph;
    }
#pragma unroll
    for (int off = 16; off; off >>= 1) mmax = fmaxf(mmax, __shfl_xor(mmax, off, 64));
    if (n1 == 0) atomicMax((int*)(magmax + b), __float_as_int(mmax));
    __syncthreads();                                // all 8 phase rows visible

    // ---- stats: gradients + Zernike over useful rows (slots 1..6) ----
    float a00 = 0.f, a11 = 0.f, a20 = 0.f, a22 = 0.f, a31 = 0.f, a33 = 0.f,
          a40 = 0.f, a42 = 0.f, a44 = 0.f, a51 = 0.f, a53 = 0.f, a55 = 0.f,
          a60 = 0.f, a62 = 0.f, a64 = 0.f, a66 = 0.f, a71 = 0.f, a73 = 0.f,
          a75 = 0.f, a77 = 0.f, a80 = 0.f, a82 = 0.f, a84 = 0.f, a86 = 0.f,
          a88 = 0.f, a91 = 0.f, a93 = 0.f, a95 = 0.f, a97 = 0.f, a99 = 0.f;
    float b11 = 0.f, b22 = 0.f, b31 = 0.f, b33 = 0.f, b42 = 0.f, b44 = 0.f,
          b51 = 0.f, b53 = 0.f, b55 = 0.f, b62 = 0.f, b64 = 0.f, b66 = 0.f,
          b71 = 0.f, b73 = 0.f, b75 = 0.f, b77 = 0.f, b82 = 0.f, b84 = 0.f,
          b86 = 0.f, b88 = 0.f, b91 = 0.f, b93 = 0.f, b95 = 0.f, b97 = 0.f,
          b99 = 0.f;
    float sgx = 0.f, sgx2 = 0.f, sgy = 0.f, sgy2 = 0.f, cnt = 0.f;

    for (int sl = 1; sl <= 6; ++sl) {
        const int k = k0 + sl - 1;
        if (k > WR - 1) break;
        const float xv = -1.0f + (1.0f / 256.0f) * (float)k;
        const float xv2 = xv * xv;
        const float* pc = (const float*)&sb[sl][0];
        const float* pm = (const float*)&sb[sl - 1][0];
        const float* pp = (const float*)&sb[sl + 1][0];
        for (int h = tid; h < 1024; h += 256) {
            const float v = pc[h];
            float gx, gy;
            if (k == 0)            gx = pp[h] - v;
            else if (k == WR - 1)  gx = v - pm[h];
            else                   gx = 0.5f * (pp[h] - pm[h]);
            if (h == 0)            gy = pc[1] - v;
            else if (h == 1023)    gy = v - pc[1022];
            else                   gy = 0.5f * (pc[h + 1] - pc[h - 1]);
            sgx += gx; sgx2 += gx * gx; sgy += gy; sgy2 += gy * gy;
            const float yv = -1.0f + (2.0f / 1023.0f) * (float)h;
            ZPIX(v, yv);
        }
    }

    WRED(a00, 0);  WRED(a11, 1);  WRED(a20, 2);  WRED(a22, 3);  WRED(a31, 4);
    WRED(a33, 5);  WRED(a40, 6);  WRED(a42, 7);  WRED(a44, 8);  WRED(a51, 9);
    WRED(a53, 10); WRED(a55, 11); WRED(a60, 12); WRED(a62, 13); WRED(a64, 14);
    WRED(a66, 15); WRED(a71, 16); WRED(a73, 17); WRED(a75, 18); WRED(a77, 19);
    WRED(a80, 20); WRED(a82, 21); WRED(a84, 22); WRED(a86, 23); WRED(a88, 24);
    WRED(a91, 25); WRED(a93, 26); WRED(a95, 27); WRED(a97, 28); WRED(a99, 29);
    WRED(b11, 30); WRED(b22, 31); WRED(b31, 32); WRED(b33, 33); WRED(b42, 34);
    WRED(b44, 35); WRED(b51, 36); WRED(b53, 37); WRED(b55, 38); WRED(b62, 39);
    WRED(b64, 40); WRED(b66, 41); WRED(b71, 42); WRED(b73, 43); WRED(b75, 44);
    WRED(b77, 45); WRED(b82, 46); WRED(b84, 47); WRED(b86, 48); WRED(b88, 49);
    WRED(b91, 50); WRED(b93, 51); WRED(b95, 52); WRED(b97, 53); WRED(b99, 54);
    WRED(sgx, 55); WRED(sgx2, 56); WRED(sgy, 57); WRED(sgy2, 58); WRED(cnt, 59);
    __syncthreads();
    if (tid < 60) {
        float sum = red[tid] + red[64 + tid] + red[128 + tid] + red[192 + tid];
        // Partial -> rf2 row (b, k0+2): disjoint from all blocks' read sets.
        float* pdst = (float*)(rf2 + ((long long)b * WR + k0 + 2) * 1024);
        pdst[tid] = sum;
    }
}

// ---------------------------------------------------------------------------
// Kernel D: sum 86 block-partials per batch, map moments -> coeffs, stats.
// ---------------------------------------------------------------------------
__device__ int moment_index(int p, int a, int is_cos) {
    int ai = 0;
    for (int pp = 0; pp < 10; ++pp)
        for (int aa = (pp & 1); aa <= pp; aa += 2) {
            if (is_cos && pp == p && aa == a) return ai;
            ++ai;
        }
    for (int pp = 1; pp < 10; ++pp)
        for (int aa = ((pp & 1) ? 1 : 2); aa <= pp; aa += 2) {
            if (!is_cos && pp == p && aa == a) return ai;
            ++ai;
        }
    return 0;
}

__device__ float factf(int n) {
    float f = 1.0f;
    for (int i = 2; i <= n; ++i) f *= (float)i;
    return f;
}

__global__ void finalize_kernel(const float* __restrict__ rf2f,
                                const float* __restrict__ magmax,
                                float* __restrict__ out) {
    __shared__ float abf[64];
    const int b = blockIdx.x;
    const int j = threadIdx.x;
    if (j < 60) {
        float s = 0.0f;
        for (int i = 0; i < 86; ++i)
            s += rf2f[((long long)b * WR + 6 * i + 2) * 2048 + j];
        abf[j] = s;
    }
    __syncthreads();
    if (j >= 60) return;
    const float NF = (float)NPIX;
    float val;
    if (j < 55) {
        int tt = j, n = 0;
        while (tt >= n + 1) { tt -= (n + 1); ++n; }
        int m = -n + 2 * tt;
        int am = m < 0 ? -m : m;
        float s = 0.0f;
        for (int k = 0; k <= (n - am) / 2; ++k) {
            float c = factf(n - k) /
                      (factf(k) * factf((n + am) / 2 - k) * factf((n - am) / 2 - k));
            if (k & 1) c = -c;
            int p = n - 2 * k;
            s += c * abf[moment_index(p, am, m >= 0 ? 1 : 0)];
        }
        val = s / abf[59];
    } else if (j == 55) {
        val = abf[55] / NF;
    } else if (j == 56) {
        val = abf[57] / NF;
    } else if (j == 57) {
        float sum = abf[55], sq = abf[56];
        val = sqrtf(fmaxf(0.0f, (sq - sum * sum / NF) / (NF - 1.0f)));
    } else if (j == 58) {
        float sum = abf[57], sq = abf[58];
        val = sqrtf(fmaxf(0.0f, (sq - sum * sum / NF) / (NF - 1.0f)));
    } else {
        val = magmax[b];
    }
    out[b * 60 + j] = val;
}

// ---------------------------------------------------------------------------
extern "C" void kernel_launch(void* const* d_in, const int* in_sizes, int n_in,
                              void* d_out, int out_size, void* d_ws, size_t ws_size,
                              hipStream_t stream) {
    (void)in_sizes; (void)n_in; (void)out_size; (void)ws_size;
    const float* x = (const float*)d_in[0];
    float* out = (float*)d_out;

    float* magmax = (float*)d_ws;                  // 32 floats (atomicMax target)
    float2* rf2 = (float2*)((char*)d_ws + 16384);  // [B][WR][H] float2 = 134.5 MB

    hipMemsetAsync(d_ws, 0, 16384, stream);
    row_fft_kernel<<<BATCH * 128, 256, 0, stream>>>(x, rf2);
    // 86 blocks x 6 useful rows cover the 513 k-rows of each batch.
    dim3 gridF(86, BATCH);
    fused_col_stats_kernel<<<gridF, 256, 0, stream>>>(rf2, magmax);
    finalize_kernel<<<BATCH, 64, 0, stream>>>((const float*)rf2, magmax, out);
}

// Round 9
// 419.462 us; speedup vs baseline: 1.2517x; 1.0552x over previous
//
#include <hip/hip_runtime.h>
#include <math.h>

#define BATCH 32
#define HH 1024
#define WW 1024
#define WR 513
#define NPIX (HH * WR)
#define TWO_PI_F 6.28318530717958647692f

// Same-wave LDS fence: wait for this wave's own LDS ops.
#define LGKM_SYNC() __asm__ __volatile__("s_waitcnt lgkmcnt(0)" ::: "memory")

__device__ __forceinline__ float2 cadd(float2 a, float2 b) { return make_float2(a.x + b.x, a.y + b.y); }
__device__ __forceinline__ float2 csub(float2 a, float2 b) { return make_float2(a.x - b.x, a.y - b.y); }
__device__ __forceinline__ float2 cmul(float2 a, float2 b) {
    return make_float2(a.x * b.x - a.y * b.y, a.x * b.y + a.y * b.x);
}

// atan2 via odd minimax poly on [0,1] (max err ~1e-5 rad) + quadrant fixup.
__device__ __forceinline__ float fast_atan2f(float y, float x) {
    float ax = __builtin_fabsf(x), ay = __builtin_fabsf(y);
    float mx = fmaxf(ax, ay), mn = fminf(ax, ay);
    float a = mn * __builtin_amdgcn_rcpf(mx);
    float s = a * a;
    float r = fmaf(fmaf(fmaf(fmaf(0.0208351f, s, -0.085133f), s, 0.180141f),
                        s, -0.3302995f), s, 0.999866f) * a;
    if (ay > ax) r = 1.5707963268f - r;
    if (x < 0.0f) r = 3.1415926536f - r;
    return (y < 0.0f) ? -r : r;
}

// ---------------- 16-point building blocks (row_fft path, unchanged) -------
__device__ __forceinline__ constexpr int ridx(int k) { return ((k & 3) << 2) | (k >> 2); }

__device__ __forceinline__ void fft16_ip(float2* d) {
    const float2 Wt1[4] = {{1.f, 0.f},
                           {0.92387953f, -0.38268343f},
                           {0.70710678f, -0.70710678f},
                           {0.38268343f, -0.92387953f}};
    const float2 Wt2[4] = {{1.f, 0.f},
                           {0.70710678f, -0.70710678f},
                           {0.f, -1.f},
                           {-0.70710678f, -0.70710678f}};
    const float2 Wt3[4] = {{1.f, 0.f},
                           {0.38268343f, -0.92387953f},
                           {-0.70710678f, -0.70710678f},
                           {-0.92387953f, 0.38268343f}};
#pragma unroll
    for (int t = 0; t < 4; ++t) {
        float2 x0 = d[t], x1 = d[t + 4], x2 = d[t + 8], x3 = d[t + 12];
        float2 a0 = cadd(x0, x2), a1 = csub(x0, x2), a2 = cadd(x1, x3), a3 = csub(x1, x3);
        d[t]      = cadd(a0, a2);
        d[t + 4]  = cmul(make_float2(a1.x + a3.y, a1.y - a3.x), Wt1[t]);
        d[t + 8]  = cmul(csub(a0, a2), Wt2[t]);
        d[t + 12] = cmul(make_float2(a1.x - a3.y, a1.y + a3.x), Wt3[t]);
    }
#pragma unroll
    for (int r = 0; r < 4; ++r) {
        float2 x0 = d[4 * r], x1 = d[4 * r + 1], x2 = d[4 * r + 2], x3 = d[4 * r + 3];
        float2 e0 = cadd(x0, x2), e1 = csub(x0, x2), e2 = cadd(x1, x3), e3 = csub(x1, x3);
        d[4 * r]     = cadd(e0, e2);
        d[4 * r + 1] = make_float2(e1.x + e3.y, e1.y - e3.x);
        d[4 * r + 2] = csub(e0, e2);
        d[4 * r + 3] = make_float2(e1.x - e3.y, e1.y + e3.x);
    }
}

__device__ __forceinline__ void twiddle_tree(float2 T, float2* Wt) {
    Wt[1] = T;
    Wt[2] = cmul(T, T);
    Wt[3] = cmul(Wt[2], T);
    Wt[4] = cmul(Wt[2], Wt[2]);
    Wt[5] = cmul(Wt[4], Wt[1]);
    Wt[6] = cmul(Wt[4], Wt[2]);
    Wt[7] = cmul(Wt[4], Wt[3]);
    Wt[8] = cmul(Wt[4], Wt[4]);
    Wt[9]  = cmul(Wt[8], Wt[1]);
    Wt[10] = cmul(Wt[8], Wt[2]);
    Wt[11] = cmul(Wt[8], Wt[3]);
    Wt[12] = cmul(Wt[8], Wt[4]);
    Wt[13] = cmul(Wt[8], Wt[5]);
    Wt[14] = cmul(Wt[8], Wt[6]);
    Wt[15] = cmul(Wt[8], Wt[7]);
}

// Wave-level 1024-pt FFT (row_fft_kernel only).
__device__ __forceinline__ void wave_fft1024(float2* v, float2* sb, int lane) {
    fft16_ip(v);
    float s, c;
    __sincosf(-TWO_PI_F * (float)lane * (1.0f / 1024.0f), &s, &c);
    float2 Wt[16];
    twiddle_tree(make_float2(c, s), Wt);
#pragma unroll
    for (int k2 = 1; k2 < 16; ++k2) v[ridx(k2)] = cmul(v[ridx(k2)], Wt[k2]);
    const int k2p = lane & 15, qp = lane >> 4;
#pragma unroll
    for (int k2 = 0; k2 < 16; ++k2) sb[(k2 << 6) | (lane ^ k2)] = v[ridx(k2)];
    LGKM_SYNC();
#pragma unroll
    for (int m = 0; m < 16; ++m) v[m] = sb[(k2p << 6) | ((4 * m + qp) ^ k2p)];
    LGKM_SYNC();
    fft16_ip(v);
    __sincosf(-TWO_PI_F * (float)qp * (1.0f / 64.0f), &s, &c);
    twiddle_tree(make_float2(c, s), Wt);
#pragma unroll
    for (int km = 1; km < 16; ++km) v[ridx(km)] = cmul(v[ridx(km)], Wt[km]);
    const bool hi2 = (lane & 32) != 0, hi1 = (lane & 16) != 0;
#pragma unroll
    for (int m = 0; m < 16; ++m) {
        float2 a = v[m];
        float2 o = make_float2(__shfl_xor(a.x, 32, 64), __shfl_xor(a.y, 32, 64));
        float2 s1 = hi2 ? csub(o, a) : cadd(a, o);
        if (hi2 && hi1) s1 = make_float2(s1.y, -s1.x);
        float2 o2 = make_float2(__shfl_xor(s1.x, 16, 64), __shfl_xor(s1.y, 16, 64));
        v[m] = hi1 ? csub(o2, s1) : cadd(s1, o2);
    }
}

// ---------------------------------------------------------------------------
// Kernel A: unchanged.
// ---------------------------------------------------------------------------
__global__ __launch_bounds__(256, 4) void row_fft_kernel(const float* __restrict__ x,
                                                         float2* __restrict__ rf2) {
    __shared__ float2 buf[4][1024];
    const int t = threadIdx.x, w = t >> 6, lane = t & 63;
    const int b = blockIdx.x >> 7;
    const int h0 = (blockIdx.x & 127) * 8;
    const float* r0 = x + ((long long)b * HH + h0 + 2 * w) * (long long)WW;
    const float* r1 = r0 + WW;
    float2 v[16];
#pragma unroll
    for (int j = 0; j < 16; ++j) v[j] = make_float2(r0[lane + 64 * j], r1[lane + 64 * j]);
    float2* mybuf = &buf[w][0];
    wave_fft1024(v, mybuf, lane);
    const int kq = 2 * ((lane >> 4) & 1) + ((lane >> 5) & 1);
    const int kbase = (lane & 15) + 256 * kq;
#pragma unroll
    for (int m = 0; m < 16; ++m) mybuf[kbase + 16 * m] = v[ridx(m)];
    __syncthreads();
    for (int idx = t; idx < 513 * 8; idx += 256) {
        int k = idx >> 3, j = idx & 7, p = j >> 1, which = j & 1;
        float2 zk = buf[p][k];
        float2 zn = buf[p][(1024 - k) & 1023];
        float2 val = which ? make_float2(0.5f * (zk.y + zn.y), 0.5f * (zn.x - zk.x))
                           : make_float2(0.5f * (zk.x + zn.x), 0.5f * (zk.y - zn.y));
        rf2[((long long)b * WR + k) * 1024 + h0 + j] = val;
    }
}

// ------------------------- 32-point FFT (four-step) ------------------------
__device__ __forceinline__ constexpr int brev5(int k) {
    return ((k & 1) << 4) | ((k & 2) << 2) | (k & 4) | ((k & 8) >> 2) | ((k & 16) >> 4);
}

__device__ __forceinline__ void fft32_dif(float2* d) {
    const float2 TW[16] = {
        {1.f, 0.f},
        {0.98078528f, -0.19509032f},
        {0.92387953f, -0.38268343f},
        {0.83146961f, -0.55557023f},
        {0.70710678f, -0.70710678f},
        {0.55557023f, -0.83146961f},
        {0.38268343f, -0.92387953f},
        {0.19509032f, -0.98078528f},
        {0.f, -1.f},
        {-0.19509032f, -0.98078528f},
        {-0.38268343f, -0.92387953f},
        {-0.55557023f, -0.83146961f},
        {-0.70710678f, -0.70710678f},
        {-0.83146961f, -0.55557023f},
        {-0.92387953f, -0.38268343f},
        {-0.98078528f, -0.19509032f}};
#pragma unroll
    for (int s = 0; s < 5; ++s) {
        const int h = 16 >> s;
#pragma unroll
        for (int b = 0; b < 32; b += 2 * h) {
#pragma unroll
            for (int j = 0; j < h; ++j) {
                float2 a = d[b + j], c = d[b + j + h];
                d[b + j]     = cadd(a, c);
                d[b + j + h] = cmul(csub(a, c), TW[j << s]);
            }
        }
    }
}

// Masked Zernike accumulation for one pixel (uses enclosing-scope names).
#define ZPIX(VV, YVV)                                                          \
    {                                                                          \
        const float yv_ = (YVV);                                               \
        const float r2_ = xv2 + yv_ * yv_;                                     \
        if (r2_ <= 1.0f) {                                                     \
            cnt += 1.0f;                                                       \
            const float rho = sqrtf(r2_);                                      \
            const float inv = rsqrtf(r2_);                                     \
            const float c1 = xv * inv;                                         \
            const float s1 = yv_ * inv;                                        \
            const float c2 = 2.f * c1 * c1 - 1.f;                              \
            const float c3 = 2.f * c1 * c2 - c1;                               \
            const float c4 = 2.f * c1 * c3 - c2;                               \
            const float c5 = 2.f * c1 * c4 - c3;                               \
            const float c6 = 2.f * c1 * c5 - c4;                               \
            const float c7 = 2.f * c1 * c6 - c5;                               \
            const float c8 = 2.f * c1 * c7 - c6;                               \
            const float c9 = 2.f * c1 * c8 - c7;                               \
            const float s2 = 2.f * c1 * s1;                                    \
            const float s3 = 2.f * c1 * s2 - s1;                               \
            const float s4 = 2.f * c1 * s3 - s2;                               \
            const float s5 = 2.f * c1 * s4 - s3;                               \
            const float s6 = 2.f * c1 * s5 - s4;                               \
            const float s7 = 2.f * c1 * s6 - s5;                               \
            const float s8 = 2.f * c1 * s7 - s6;                               \
            const float s9 = 2.f * c1 * s8 - s7;                               \
            const float w0 = (VV), w1 = w0 * rho, w2 = w1 * rho, w3 = w2 * rho,\
                        w4 = w3 * rho, w5 = w4 * rho, w6 = w5 * rho,           \
                        w7 = w6 * rho, w8 = w7 * rho, w9 = w8 * rho;           \
            a00 += w0;                                                         \
            a11 += w1 * c1;                                                    \
            a20 += w2;      a22 += w2 * c2;                                    \
            a31 += w3 * c1; a33 += w3 * c3;                                    \
            a40 += w4;      a42 += w4 * c2; a44 += w4 * c4;                    \
            a51 += w5 * c1; a53 += w5 * c3; a55 += w5 * c5;                    \
            a60 += w6;      a62 += w6 * c2; a64 += w6 * c4; a66 += w6 * c6;    \
            a71 += w7 * c1; a73 += w7 * c3; a75 += w7 * c5; a77 += w7 * c7;    \
            a80 += w8;      a82 += w8 * c2; a84 += w8 * c4; a86 += w8 * c6;    \
            a88 += w8 * c8;                                                    \
            a91 += w9 * c1; a93 += w9 * c3; a95 += w9 * c5; a97 += w9 * c7;    \
            a99 += w9 * c9;                                                    \
            b11 += w1 * s1;                                                    \
            b22 += w2 * s2;                                                    \
            b31 += w3 * s1; b33 += w3 * s3;                                    \
            b42 += w4 * s2; b44 += w4 * s4;                                    \
            b51 += w5 * s1; b53 += w5 * s3; b55 += w5 * s5;                    \
            b62 += w6 * s2; b64 += w6 * s4; b66 += w6 * s6;                    \
            b71 += w7 * s1; b73 += w7 * s3; b75 += w7 * s5; b77 += w7 * s7;    \
            b82 += w8 * s2; b84 += w8 * s4; b86 += w8 * s6; b88 += w8 * s8;    \
            b91 += w9 * s1; b93 += w9 * s3; b95 += w9 * s5; b97 += w9 * s7;    \
            b99 += w9 * s9;                                                    \
        }                                                                      \
    }

#define WRED(var, idx)                                                     \
    {                                                                      \
        float r_ = var;                                                    \
        _Pragma("unroll")                                                  \
        for (int off_ = 32; off_; off_ >>= 1) r_ += __shfl_down(r_, off_); \
        if (lane == 0) red[w * 64 + (idx)] = r_;                           \
    }

// ---------------------------------------------------------------------------
// Kernel B (FUSED col FFT + stats), occupancy edition. R8 measured: fusion
// worked (WRITE 66->1 MB, VALUBusy 16->48%) but LDS=64KB caps at 2 blocks/CU
// (20% occupancy) and VALUBusy 48% = waves stalled half the time on LDS
// latency with nothing to fill. Fixes:
//  (1) LDS 64->33 KB: transpose .x/.y in TWO b32 passes through the 4 KB
//      phase buffer itself (XOR swizzle k1*32+(n1^k1); every wave64 access
//      = 2 lanes/bank = free). 160/33 -> 4 blocks/CU; VGPR 128 -> 16 waves/CU.
//  (2) float4 stats reads: each thread owns 4 consecutive pixels; 3x
//      ds_read_b128 + 2 scalars per 4 pixels instead of ~20 scalar reads.
// launch_bounds(256,4) pins the 128-VGPR cap (watch WRITE_SIZE for spills).
// Partial target rf2 row (b, k0+2): disjointness proof unchanged from R8.
// ---------------------------------------------------------------------------
__global__ __launch_bounds__(256, 4) void fused_col_stats_kernel(float2* __restrict__ rf2,
                                                                 float* __restrict__ magmax) {
    __shared__ float sb[8][1024];       // 32 KB: per-slot scratch, then phases
    __shared__ float red[256];          // 1 KB reduction buffer
    const int tid = threadIdx.x, w = tid >> 6, lane = tid & 63;
    const int n1 = lane & 31, s = lane >> 5;
    const int slot = 2 * w + s;                     // 0..7 = rows k0-1 .. k0+6
    const int bx = blockIdx.x, b = blockIdx.y;
    const int k0 = bx * 6;
    int kf = k0 - 1 + slot;
    kf = kf < 0 ? 0 : (kf > WR - 1 ? WR - 1 : kf);  // clamped halo (dupes unused)
    const float2* src = rf2 + ((long long)b * WR + kf) * 1024;

    // ---- four-step 1024-pt FFT over this slot's row ----
    float2 d[32];
#pragma unroll
    for (int j = 0; j < 32; ++j) d[j] = src[n1 + 32 * j];
    fft32_dif(d);                                   // d[brev5(k1)] = A[n1][k1]
    float s0, c0;
    __sincosf(-TWO_PI_F * (float)n1 * (1.0f / 1024.0f), &s0, &c0);
    const float2 Tn = make_float2(c0, s0);
    float2 ww = Tn;
#pragma unroll
    for (int k1 = 1; k1 < 32; ++k1) {
        d[brev5(k1)] = cmul(d[brev5(k1)], ww);
        if (k1 < 31) ww = cmul(ww, Tn);
    }
    // Two-pass b32 transpose through the 4 KB slot (XOR swizzle, 2 lanes/bank).
    float* scr = &sb[slot][0];
#pragma unroll
    for (int k1 = 0; k1 < 32; ++k1) scr[(k1 << 5) | (n1 ^ k1)] = d[brev5(k1)].x;
    LGKM_SYNC();
    float tx[32];
#pragma unroll
    for (int j = 0; j < 32; ++j) tx[j] = scr[(n1 << 5) | (j ^ n1)];
    LGKM_SYNC();                        // .x reads done before .y overwrite
#pragma unroll
    for (int k1 = 0; k1 < 32; ++k1) scr[(k1 << 5) | (n1 ^ k1)] = d[brev5(k1)].y;
    LGKM_SYNC();
#pragma unroll
    for (int j = 0; j < 32; ++j) d[j] = make_float2(tx[j], scr[(n1 << 5) | (j ^ n1)]);
    fft32_dif(d);                                   // d[brev5(k2)] = X[n1 + 32*k2]

    // ---- epilogue: phase -> LDS (same slot; DS in-order + data dep), mag ----
    float mmax = 0.0f;
#pragma unroll
    for (int k2 = 0; k2 < 32; ++k2) {
        float2 z = d[brev5(k2)];
        mmax = fmaxf(mmax, __builtin_amdgcn_sqrtf(z.x * z.x + z.y * z.y));
        float ph = fast_atan2f(z.y, z.x);
        scr[32 * k2 + n1] = (ph < 0.0f) ? ph + TWO_PI_F : ph;   // == phase[h]
    }
#pragma unroll
    for (int off = 16; off; off >>= 1) mmax = fmaxf(mmax, __shfl_xor(mmax, off, 64));
    if (n1 == 0) atomicMax((int*)(magmax + b), __float_as_int(mmax));
    __syncthreads();                                // all 8 phase rows visible

    // ---- stats: float4 per thread per row (h4 = tid*4 covers 0..1023) ----
    float a00 = 0.f, a11 = 0.f, a20 = 0.f, a22 = 0.f, a31 = 0.f, a33 = 0.f,
          a40 = 0.f, a42 = 0.f, a44 = 0.f, a51 = 0.f, a53 = 0.f, a55 = 0.f,
          a60 = 0.f, a62 = 0.f, a64 = 0.f, a66 = 0.f, a71 = 0.f, a73 = 0.f,
          a75 = 0.f, a77 = 0.f, a80 = 0.f, a82 = 0.f, a84 = 0.f, a86 = 0.f,
          a88 = 0.f, a91 = 0.f, a93 = 0.f, a95 = 0.f, a97 = 0.f, a99 = 0.f;
    float b11 = 0.f, b22 = 0.f, b31 = 0.f, b33 = 0.f, b42 = 0.f, b44 = 0.f,
          b51 = 0.f, b53 = 0.f, b55 = 0.f, b62 = 0.f, b64 = 0.f, b66 = 0.f,
          b71 = 0.f, b73 = 0.f, b75 = 0.f, b77 = 0.f, b82 = 0.f, b84 = 0.f,
          b86 = 0.f, b88 = 0.f, b91 = 0.f, b93 = 0.f, b95 = 0.f, b97 = 0.f,
          b99 = 0.f;
    float sgx = 0.f, sgx2 = 0.f, sgy = 0.f, sgy2 = 0.f, cnt = 0.f;

    const int h4 = tid * 4;
    const float ystep = 2.0f / 1023.0f;
    const float yv0 = -1.0f + ystep * (float)h4;

    for (int sl = 1; sl <= 6; ++sl) {
        const int k = k0 + sl - 1;
        if (k > WR - 1) break;
        const float xv = -1.0f + (1.0f / 256.0f) * (float)k;
        const float xv2 = xv * xv;
        const float* pc = &sb[sl][0];
        const float* pm = &sb[sl - 1][0];
        const float* pp = &sb[sl + 1][0];
        const float4 vc = *reinterpret_cast<const float4*>(pc + h4);
        float4 gx4;
        if (k == 0) {
            const float4 vp = *reinterpret_cast<const float4*>(pp + h4);
            gx4 = make_float4(vp.x - vc.x, vp.y - vc.y, vp.z - vc.z, vp.w - vc.w);
        } else if (k == WR - 1) {
            const float4 vm = *reinterpret_cast<const float4*>(pm + h4);
            gx4 = make_float4(vc.x - vm.x, vc.y - vm.y, vc.z - vm.z, vc.w - vm.w);
        } else {
            const float4 vm = *reinterpret_cast<const float4*>(pm + h4);
            const float4 vp = *reinterpret_cast<const float4*>(pp + h4);
            gx4 = make_float4(0.5f * (vp.x - vm.x), 0.5f * (vp.y - vm.y),
                              0.5f * (vp.z - vm.z), 0.5f * (vp.w - vm.w));
        }
        const float left  = pc[h4 > 0 ? h4 - 1 : 0];
        const float right = pc[h4 < 1020 ? h4 + 4 : 1023];
        const float gy0 = (h4 == 0)    ? vc.y - vc.x : 0.5f * (vc.y - left);
        const float gy1 = 0.5f * (vc.z - vc.x);
        const float gy2 = 0.5f * (vc.w - vc.y);
        const float gy3 = (h4 == 1020) ? vc.w - vc.z : 0.5f * (right - vc.z);

        sgx  += gx4.x + gx4.y + gx4.z + gx4.w;
        sgx2 += gx4.x * gx4.x + gx4.y * gx4.y + gx4.z * gx4.z + gx4.w * gx4.w;
        sgy  += gy0 + gy1 + gy2 + gy3;
        sgy2 += gy0 * gy0 + gy1 * gy1 + gy2 * gy2 + gy3 * gy3;

        ZPIX(vc.x, yv0);
        ZPIX(vc.y, yv0 + ystep);
        ZPIX(vc.z, yv0 + 2.0f * ystep);
        ZPIX(vc.w, yv0 + 3.0f * ystep);
    }

    WRED(a00, 0);  WRED(a11, 1);  WRED(a20, 2);  WRED(a22, 3);  WRED(a31, 4);
    WRED(a33, 5);  WRED(a40, 6);  WRED(a42, 7);  WRED(a44, 8);  WRED(a51, 9);
    WRED(a53, 10); WRED(a55, 11); WRED(a60, 12); WRED(a62, 13); WRED(a64, 14);
    WRED(a66, 15); WRED(a71, 16); WRED(a73, 17); WRED(a75, 18); WRED(a77, 19);
    WRED(a80, 20); WRED(a82, 21); WRED(a84, 22); WRED(a86, 23); WRED(a88, 24);
    WRED(a91, 25); WRED(a93, 26); WRED(a95, 27); WRED(a97, 28); WRED(a99, 29);
    WRED(b11, 30); WRED(b22, 31); WRED(b31, 32); WRED(b33, 33); WRED(b42, 34);
    WRED(b44, 35); WRED(b51, 36); WRED(b53, 37); WRED(b55, 38); WRED(b62, 39);
    WRED(b64, 40); WRED(b66, 41); WRED(b71, 42); WRED(b73, 43); WRED(b75, 44);
    WRED(b77, 45); WRED(b82, 46); WRED(b84, 47); WRED(b86, 48); WRED(b88, 49);
    WRED(b91, 50); WRED(b93, 51); WRED(b95, 52); WRED(b97, 53); WRED(b99, 54);
    WRED(sgx, 55); WRED(sgx2, 56); WRED(sgy, 57); WRED(sgy2, 58); WRED(cnt, 59);
    __syncthreads();
    if (tid < 60) {
        float sum = red[tid] + red[64 + tid] + red[128 + tid] + red[192 + tid];
        // Partial -> rf2 row (b, k0+2): disjoint from all blocks' read sets.
        float* pdst = (float*)(rf2 + ((long long)b * WR + k0 + 2) * 1024);
        pdst[tid] = sum;
    }
}

// ---------------------------------------------------------------------------
// Kernel D: sum 86 block-partials per batch, map moments -> coeffs, stats.
// ---------------------------------------------------------------------------
__device__ int moment_index(int p, int a, int is_cos) {
    int ai = 0;
    for (int pp = 0; pp < 10; ++pp)
        for (int aa = (pp & 1); aa <= pp; aa += 2) {
            if (is_cos && pp == p && aa == a) return ai;
            ++ai;
        }
    for (int pp = 1; pp < 10; ++pp)
        for (int aa = ((pp & 1) ? 1 : 2); aa <= pp; aa += 2) {
            if (!is_cos && pp == p && aa == a) return ai;
            ++ai;
        }
    return 0;
}

__device__ float factf(int n) {
    float f = 1.0f;
    for (int i = 2; i <= n; ++i) f *= (float)i;
    return f;
}

__global__ void finalize_kernel(const float* __restrict__ rf2f,
                                const float* __restrict__ magmax,
                                float* __restrict__ out) {
    __shared__ float abf[64];
    const int b = blockIdx.x;
    const int j = threadIdx.x;
    if (j < 60) {
        float s = 0.0f;
        for (int i = 0; i < 86; ++i)
            s += rf2f[((long long)b * WR + 6 * i + 2) * 2048 + j];
        abf[j] = s;
    }
    __syncthreads();
    if (j >= 60) return;
    const float NF = (float)NPIX;
    float val;
    if (j < 55) {
        int tt = j, n = 0;
        while (tt >= n + 1) { tt -= (n + 1); ++n; }
        int m = -n + 2 * tt;
        int am = m < 0 ? -m : m;
        float s = 0.0f;
        for (int k = 0; k <= (n - am) / 2; ++k) {
            float c = factf(n - k) /
                      (factf(k) * factf((n + am) / 2 - k) * factf((n - am) / 2 - k));
            if (k & 1) c = -c;
            int p = n - 2 * k;
            s += c * abf[moment_index(p, am, m >= 0 ? 1 : 0)];
        }
        val = s / abf[59];
    } else if (j == 55) {
        val = abf[55] / NF;
    } else if (j == 56) {
        val = abf[57] / NF;
    } else if (j == 57) {
        float sum = abf[55], sq = abf[56];
        val = sqrtf(fmaxf(0.0f, (sq - sum * sum / NF) / (NF - 1.0f)));
    } else if (j == 58) {
        float sum = abf[57], sq = abf[58];
        val = sqrtf(fmaxf(0.0f, (sq - sum * sum / NF) / (NF - 1.0f)));
    } else {
        val = magmax[b];
    }
    out[b * 60 + j] = val;
}

// ---------------------------------------------------------------------------
extern "C" void kernel_launch(void* const* d_in, const int* in_sizes, int n_in,
                              void* d_out, int out_size, void* d_ws, size_t ws_size,
                              hipStream_t stream) {
    (void)in_sizes; (void)n_in; (void)out_size; (void)ws_size;
    const float* x = (const float*)d_in[0];
    float* out = (float*)d_out;

    float* magmax = (float*)d_ws;                  // 32 floats (atomicMax target)
    float2* rf2 = (float2*)((char*)d_ws + 16384);  // [B][WR][H] float2 = 134.5 MB

    hipMemsetAsync(d_ws, 0, 16384, stream);
    row_fft_kernel<<<BATCH * 128, 256, 0, stream>>>(x, rf2);
    // 86 blocks x 6 useful rows cover the 513 k-rows of each batch.
    dim3 gridF(86, BATCH);
    fused_col_stats_kernel<<<gridF, 256, 0, stream>>>(rf2, magmax);
    finalize_kernel<<<BATCH, 64, 0, stream>>>((const float*)rf2, magmax, out);
}

// Round 10
// 413.831 us; speedup vs baseline: 1.2688x; 1.0136x over previous
//
#include <hip/hip_runtime.h>
#include <math.h>

#define BATCH 32
#define HH 1024
#define WW 1024
#define WR 513
#define NPIX (HH * WR)
#define TWO_PI_F 6.28318530717958647692f

// Same-wave LDS fence: wait for this wave's own LDS ops.
#define LGKM_SYNC() __asm__ __volatile__("s_waitcnt lgkmcnt(0)" ::: "memory")

__device__ __forceinline__ float2 cadd(float2 a, float2 b) { return make_float2(a.x + b.x, a.y + b.y); }
__device__ __forceinline__ float2 csub(float2 a, float2 b) { return make_float2(a.x - b.x, a.y - b.y); }
__device__ __forceinline__ float2 cmul(float2 a, float2 b) {
    return make_float2(a.x * b.x - a.y * b.y, a.x * b.y + a.y * b.x);
}

// atan2 via odd minimax poly on [0,1] (max err ~1e-5 rad) + quadrant fixup.
__device__ __forceinline__ float fast_atan2f(float y, float x) {
    float ax = __builtin_fabsf(x), ay = __builtin_fabsf(y);
    float mx = fmaxf(ax, ay), mn = fminf(ax, ay);
    float a = mn * __builtin_amdgcn_rcpf(mx);
    float s = a * a;
    float r = fmaf(fmaf(fmaf(fmaf(0.0208351f, s, -0.085133f), s, 0.180141f),
                        s, -0.3302995f), s, 0.999866f) * a;
    if (ay > ax) r = 1.5707963268f - r;
    if (x < 0.0f) r = 3.1415926536f - r;
    return (y < 0.0f) ? -r : r;
}

// ---------------- 16-point building blocks (row_fft path, unchanged) -------
__device__ __forceinline__ constexpr int ridx(int k) { return ((k & 3) << 2) | (k >> 2); }

__device__ __forceinline__ void fft16_ip(float2* d) {
    const float2 Wt1[4] = {{1.f, 0.f},
                           {0.92387953f, -0.38268343f},
                           {0.70710678f, -0.70710678f},
                           {0.38268343f, -0.92387953f}};
    const float2 Wt2[4] = {{1.f, 0.f},
                           {0.70710678f, -0.70710678f},
                           {0.f, -1.f},
                           {-0.70710678f, -0.70710678f}};
    const float2 Wt3[4] = {{1.f, 0.f},
                           {0.38268343f, -0.92387953f},
                           {-0.70710678f, -0.70710678f},
                           {-0.92387953f, 0.38268343f}};
#pragma unroll
    for (int t = 0; t < 4; ++t) {
        float2 x0 = d[t], x1 = d[t + 4], x2 = d[t + 8], x3 = d[t + 12];
        float2 a0 = cadd(x0, x2), a1 = csub(x0, x2), a2 = cadd(x1, x3), a3 = csub(x1, x3);
        d[t]      = cadd(a0, a2);
        d[t + 4]  = cmul(make_float2(a1.x + a3.y, a1.y - a3.x), Wt1[t]);
        d[t + 8]  = cmul(csub(a0, a2), Wt2[t]);
        d[t + 12] = cmul(make_float2(a1.x - a3.y, a1.y + a3.x), Wt3[t]);
    }
#pragma unroll
    for (int r = 0; r < 4; ++r) {
        float2 x0 = d[4 * r], x1 = d[4 * r + 1], x2 = d[4 * r + 2], x3 = d[4 * r + 3];
        float2 e0 = cadd(x0, x2), e1 = csub(x0, x2), e2 = cadd(x1, x3), e3 = csub(x1, x3);
        d[4 * r]     = cadd(e0, e2);
        d[4 * r + 1] = make_float2(e1.x + e3.y, e1.y - e3.x);
        d[4 * r + 2] = csub(e0, e2);
        d[4 * r + 3] = make_float2(e1.x - e3.y, e1.y + e3.x);
    }
}

__device__ __forceinline__ void twiddle_tree(float2 T, float2* Wt) {
    Wt[1] = T;
    Wt[2] = cmul(T, T);
    Wt[3] = cmul(Wt[2], T);
    Wt[4] = cmul(Wt[2], Wt[2]);
    Wt[5] = cmul(Wt[4], Wt[1]);
    Wt[6] = cmul(Wt[4], Wt[2]);
    Wt[7] = cmul(Wt[4], Wt[3]);
    Wt[8] = cmul(Wt[4], Wt[4]);
    Wt[9]  = cmul(Wt[8], Wt[1]);
    Wt[10] = cmul(Wt[8], Wt[2]);
    Wt[11] = cmul(Wt[8], Wt[3]);
    Wt[12] = cmul(Wt[8], Wt[4]);
    Wt[13] = cmul(Wt[8], Wt[5]);
    Wt[14] = cmul(Wt[8], Wt[6]);
    Wt[15] = cmul(Wt[8], Wt[7]);
}

// Wave-level 1024-pt FFT (row_fft_kernel only).
__device__ __forceinline__ void wave_fft1024(float2* v, float2* sb, int lane) {
    fft16_ip(v);
    float s, c;
    __sincosf(-TWO_PI_F * (float)lane * (1.0f / 1024.0f), &s, &c);
    float2 Wt[16];
    twiddle_tree(make_float2(c, s), Wt);
#pragma unroll
    for (int k2 = 1; k2 < 16; ++k2) v[ridx(k2)] = cmul(v[ridx(k2)], Wt[k2]);
    const int k2p = lane & 15, qp = lane >> 4;
#pragma unroll
    for (int k2 = 0; k2 < 16; ++k2) sb[(k2 << 6) | (lane ^ k2)] = v[ridx(k2)];
    LGKM_SYNC();
#pragma unroll
    for (int m = 0; m < 16; ++m) v[m] = sb[(k2p << 6) | ((4 * m + qp) ^ k2p)];
    LGKM_SYNC();
    fft16_ip(v);
    __sincosf(-TWO_PI_F * (float)qp * (1.0f / 64.0f), &s, &c);
    twiddle_tree(make_float2(c, s), Wt);
#pragma unroll
    for (int km = 1; km < 16; ++km) v[ridx(km)] = cmul(v[ridx(km)], Wt[km]);
    const bool hi2 = (lane & 32) != 0, hi1 = (lane & 16) != 0;
#pragma unroll
    for (int m = 0; m < 16; ++m) {
        float2 a = v[m];
        float2 o = make_float2(__shfl_xor(a.x, 32, 64), __shfl_xor(a.y, 32, 64));
        float2 s1 = hi2 ? csub(o, a) : cadd(a, o);
        if (hi2 && hi1) s1 = make_float2(s1.y, -s1.x);
        float2 o2 = make_float2(__shfl_xor(s1.x, 16, 64), __shfl_xor(s1.y, 16, 64));
        v[m] = hi1 ? csub(o2, s1) : cadd(s1, o2);
    }
}

// ---------------------------------------------------------------------------
// Kernel A: unchanged.
// ---------------------------------------------------------------------------
__global__ __launch_bounds__(256, 4) void row_fft_kernel(const float* __restrict__ x,
                                                         float2* __restrict__ rf2) {
    __shared__ float2 buf[4][1024];
    const int t = threadIdx.x, w = t >> 6, lane = t & 63;
    const int b = blockIdx.x >> 7;
    const int h0 = (blockIdx.x & 127) * 8;
    const float* r0 = x + ((long long)b * HH + h0 + 2 * w) * (long long)WW;
    const float* r1 = r0 + WW;
    float2 v[16];
#pragma unroll
    for (int j = 0; j < 16; ++j) v[j] = make_float2(r0[lane + 64 * j], r1[lane + 64 * j]);
    float2* mybuf = &buf[w][0];
    wave_fft1024(v, mybuf, lane);
    const int kq = 2 * ((lane >> 4) & 1) + ((lane >> 5) & 1);
    const int kbase = (lane & 15) + 256 * kq;
#pragma unroll
    for (int m = 0; m < 16; ++m) mybuf[kbase + 16 * m] = v[ridx(m)];
    __syncthreads();
    for (int idx = t; idx < 513 * 8; idx += 256) {
        int k = idx >> 3, j = idx & 7, p = j >> 1, which = j & 1;
        float2 zk = buf[p][k];
        float2 zn = buf[p][(1024 - k) & 1023];
        float2 val = which ? make_float2(0.5f * (zk.y + zn.y), 0.5f * (zn.x - zk.x))
                           : make_float2(0.5f * (zk.x + zn.x), 0.5f * (zk.y - zn.y));
        rf2[((long long)b * WR + k) * 1024 + h0 + j] = val;
    }
}

// ------------------------- 32-point FFT (four-step) ------------------------
__device__ __forceinline__ constexpr int brev5(int k) {
    return ((k & 1) << 4) | ((k & 2) << 2) | (k & 4) | ((k & 8) >> 2) | ((k & 16) >> 4);
}

__device__ __forceinline__ void fft32_dif(float2* d) {
    const float2 TW[16] = {
        {1.f, 0.f},
        {0.98078528f, -0.19509032f},
        {0.92387953f, -0.38268343f},
        {0.83146961f, -0.55557023f},
        {0.70710678f, -0.70710678f},
        {0.55557023f, -0.83146961f},
        {0.38268343f, -0.92387953f},
        {0.19509032f, -0.98078528f},
        {0.f, -1.f},
        {-0.19509032f, -0.98078528f},
        {-0.38268343f, -0.92387953f},
        {-0.55557023f, -0.83146961f},
        {-0.70710678f, -0.70710678f},
        {-0.83146961f, -0.55557023f},
        {-0.92387953f, -0.38268343f},
        {-0.98078528f, -0.19509032f}};
#pragma unroll
    for (int s = 0; s < 5; ++s) {
        const int h = 16 >> s;
#pragma unroll
        for (int b = 0; b < 32; b += 2 * h) {
#pragma unroll
            for (int j = 0; j < h; ++j) {
                float2 a = d[b + j], c = d[b + j + h];
                d[b + j]     = cadd(a, c);
                d[b + j + h] = cmul(csub(a, c), TW[j << s]);
            }
        }
    }
}

// Masked Zernike accumulation for one pixel (uses enclosing-scope names).
#define ZPIX(VV, YVV)                                                          \
    {                                                                          \
        const float yv_ = (YVV);                                               \
        const float r2_ = xv2 + yv_ * yv_;                                     \
        if (r2_ <= 1.0f) {                                                     \
            cnt += 1.0f;                                                       \
            const float rho = sqrtf(r2_);                                      \
            const float inv = rsqrtf(r2_);                                     \
            const float c1 = xv * inv;                                         \
            const float s1 = yv_ * inv;                                        \
            const float c2 = 2.f * c1 * c1 - 1.f;                              \
            const float c3 = 2.f * c1 * c2 - c1;                               \
            const float c4 = 2.f * c1 * c3 - c2;                               \
            const float c5 = 2.f * c1 * c4 - c3;                               \
            const float c6 = 2.f * c1 * c5 - c4;                               \
            const float c7 = 2.f * c1 * c6 - c5;                               \
            const float c8 = 2.f * c1 * c7 - c6;                               \
            const float c9 = 2.f * c1 * c8 - c7;                               \
            const float s2 = 2.f * c1 * s1;                                    \
            const float s3 = 2.f * c1 * s2 - s1;                               \
            const float s4 = 2.f * c1 * s3 - s2;                               \
            const float s5 = 2.f * c1 * s4 - s3;                               \
            const float s6 = 2.f * c1 * s5 - s4;                               \
            const float s7 = 2.f * c1 * s6 - s5;                               \
            const float s8 = 2.f * c1 * s7 - s6;                               \
            const float s9 = 2.f * c1 * s8 - s7;                               \
            const float w0 = (VV), w1 = w0 * rho, w2 = w1 * rho, w3 = w2 * rho,\
                        w4 = w3 * rho, w5 = w4 * rho, w6 = w5 * rho,           \
                        w7 = w6 * rho, w8 = w7 * rho, w9 = w8 * rho;           \
            a00 += w0;                                                         \
            a11 += w1 * c1;                                                    \
            a20 += w2;      a22 += w2 * c2;                                    \
            a31 += w3 * c1; a33 += w3 * c3;                                    \
            a40 += w4;      a42 += w4 * c2; a44 += w4 * c4;                    \
            a51 += w5 * c1; a53 += w5 * c3; a55 += w5 * c5;                    \
            a60 += w6;      a62 += w6 * c2; a64 += w6 * c4; a66 += w6 * c6;    \
            a71 += w7 * c1; a73 += w7 * c3; a75 += w7 * c5; a77 += w7 * c7;    \
            a80 += w8;      a82 += w8 * c2; a84 += w8 * c4; a86 += w8 * c6;    \
            a88 += w8 * c8;                                                    \
            a91 += w9 * c1; a93 += w9 * c3; a95 += w9 * c5; a97 += w9 * c7;    \
            a99 += w9 * c9;                                                    \
            b11 += w1 * s1;                                                    \
            b22 += w2 * s2;                                                    \
            b31 += w3 * s1; b33 += w3 * s3;                                    \
            b42 += w4 * s2; b44 += w4 * s4;                                    \
            b51 += w5 * s1; b53 += w5 * s3; b55 += w5 * s5;                    \
            b62 += w6 * s2; b64 += w6 * s4; b66 += w6 * s6;                    \
            b71 += w7 * s1; b73 += w7 * s3; b75 += w7 * s5; b77 += w7 * s7;    \
            b82 += w8 * s2; b84 += w8 * s4; b86 += w8 * s6; b88 += w8 * s8;    \
            b91 += w9 * s1; b93 += w9 * s3; b95 += w9 * s5; b97 += w9 * s7;    \
            b99 += w9 * s9;                                                    \
        }                                                                      \
    }

#define WRED(var, idx)                                                     \
    {                                                                      \
        float r_ = var;                                                    \
        _Pragma("unroll")                                                  \
        for (int off_ = 32; off_; off_ >>= 1) r_ += __shfl_down(r_, off_); \
        if (lane == 0) red[w * 64 + (idx)] = r_;                           \
    }

// ---------------------------------------------------------------------------
// Kernel B (FUSED col FFT + stats), spill-free edition. R9 measured: the
// compiler's VGPR cap model is 256/min_waves_per_EU — (256,4) forced VGPR=64,
// but d[32] alone is 64 VGPRs -> ~19MB spill writes (WRITE 1->20MB) + reloads.
// Fix: launch_bounds(256,2) -> 128-VGPR cap; peak live set d[32](64) +
// tx[32](32) + misc(~20) = ~116 fits. Occupancy follows ACTUAL resources,
// and both LDS (33KB -> 4 blocks/CU) and VGPR (128 -> 4 waves/SIMD) allow
// 16 waves/CU — same as R9's measured 35%, now without scratch traffic.
// (R8's 20% was capped by its 64KB LDS, not the launch bound.)
// Partial target rf2 row (b, k0+2): disjointness proof unchanged from R8.
// ---------------------------------------------------------------------------
__global__ __launch_bounds__(256, 2) void fused_col_stats_kernel(float2* __restrict__ rf2,
                                                                 float* __restrict__ magmax) {
    __shared__ float sb[8][1024];       // 32 KB: per-slot scratch, then phases
    __shared__ float red[256];          // 1 KB reduction buffer
    const int tid = threadIdx.x, w = tid >> 6, lane = tid & 63;
    const int n1 = lane & 31, s = lane >> 5;
    const int slot = 2 * w + s;                     // 0..7 = rows k0-1 .. k0+6
    const int bx = blockIdx.x, b = blockIdx.y;
    const int k0 = bx * 6;
    int kf = k0 - 1 + slot;
    kf = kf < 0 ? 0 : (kf > WR - 1 ? WR - 1 : kf);  // clamped halo (dupes unused)
    const float2* src = rf2 + ((long long)b * WR + kf) * 1024;

    // ---- four-step 1024-pt FFT over this slot's row ----
    float2 d[32];
#pragma unroll
    for (int j = 0; j < 32; ++j) d[j] = src[n1 + 32 * j];
    fft32_dif(d);                                   // d[brev5(k1)] = A[n1][k1]
    float s0, c0;
    __sincosf(-TWO_PI_F * (float)n1 * (1.0f / 1024.0f), &s0, &c0);
    const float2 Tn = make_float2(c0, s0);
    float2 ww = Tn;
#pragma unroll
    for (int k1 = 1; k1 < 32; ++k1) {
        d[brev5(k1)] = cmul(d[brev5(k1)], ww);
        if (k1 < 31) ww = cmul(ww, Tn);
    }
    // Two-pass b32 transpose through the 4 KB slot (XOR swizzle, 2 lanes/bank).
    float* scr = &sb[slot][0];
#pragma unroll
    for (int k1 = 0; k1 < 32; ++k1) scr[(k1 << 5) | (n1 ^ k1)] = d[brev5(k1)].x;
    LGKM_SYNC();
    float tx[32];
#pragma unroll
    for (int j = 0; j < 32; ++j) tx[j] = scr[(n1 << 5) | (j ^ n1)];
    LGKM_SYNC();                        // .x reads done before .y overwrite
#pragma unroll
    for (int k1 = 0; k1 < 32; ++k1) scr[(k1 << 5) | (n1 ^ k1)] = d[brev5(k1)].y;
    LGKM_SYNC();
#pragma unroll
    for (int j = 0; j < 32; ++j) d[j] = make_float2(tx[j], scr[(n1 << 5) | (j ^ n1)]);
    fft32_dif(d);                                   // d[brev5(k2)] = X[n1 + 32*k2]

    // ---- epilogue: phase -> LDS (same slot; DS in-order + data dep), mag ----
    float mmax = 0.0f;
#pragma unroll
    for (int k2 = 0; k2 < 32; ++k2) {
        float2 z = d[brev5(k2)];
        mmax = fmaxf(mmax, __builtin_amdgcn_sqrtf(z.x * z.x + z.y * z.y));
        float ph = fast_atan2f(z.y, z.x);
        scr[32 * k2 + n1] = (ph < 0.0f) ? ph + TWO_PI_F : ph;   // == phase[h]
    }
#pragma unroll
    for (int off = 16; off; off >>= 1) mmax = fmaxf(mmax, __shfl_xor(mmax, off, 64));
    if (n1 == 0) atomicMax((int*)(magmax + b), __float_as_int(mmax));
    __syncthreads();                                // all 8 phase rows visible

    // ---- stats: float4 per thread per row (h4 = tid*4 covers 0..1023) ----
    float a00 = 0.f, a11 = 0.f, a20 = 0.f, a22 = 0.f, a31 = 0.f, a33 = 0.f,
          a40 = 0.f, a42 = 0.f, a44 = 0.f, a51 = 0.f, a53 = 0.f, a55 = 0.f,
          a60 = 0.f, a62 = 0.f, a64 = 0.f, a66 = 0.f, a71 = 0.f, a73 = 0.f,
          a75 = 0.f, a77 = 0.f, a80 = 0.f, a82 = 0.f, a84 = 0.f, a86 = 0.f,
          a88 = 0.f, a91 = 0.f, a93 = 0.f, a95 = 0.f, a97 = 0.f, a99 = 0.f;
    float b11 = 0.f, b22 = 0.f, b31 = 0.f, b33 = 0.f, b42 = 0.f, b44 = 0.f,
          b51 = 0.f, b53 = 0.f, b55 = 0.f, b62 = 0.f, b64 = 0.f, b66 = 0.f,
          b71 = 0.f, b73 = 0.f, b75 = 0.f, b77 = 0.f, b82 = 0.f, b84 = 0.f,
          b86 = 0.f, b88 = 0.f, b91 = 0.f, b93 = 0.f, b95 = 0.f, b97 = 0.f,
          b99 = 0.f;
    float sgx = 0.f, sgx2 = 0.f, sgy = 0.f, sgy2 = 0.f, cnt = 0.f;

    const int h4 = tid * 4;
    const float ystep = 2.0f / 1023.0f;
    const float yv0 = -1.0f + ystep * (float)h4;

    for (int sl = 1; sl <= 6; ++sl) {
        const int k = k0 + sl - 1;
        if (k > WR - 1) break;
        const float xv = -1.0f + (1.0f / 256.0f) * (float)k;
        const float xv2 = xv * xv;
        const float* pc = &sb[sl][0];
        const float* pm = &sb[sl - 1][0];
        const float* pp = &sb[sl + 1][0];
        const float4 vc = *reinterpret_cast<const float4*>(pc + h4);
        float4 gx4;
        if (k == 0) {
            const float4 vp = *reinterpret_cast<const float4*>(pp + h4);
            gx4 = make_float4(vp.x - vc.x, vp.y - vc.y, vp.z - vc.z, vp.w - vc.w);
        } else if (k == WR - 1) {
            const float4 vm = *reinterpret_cast<const float4*>(pm + h4);
            gx4 = make_float4(vc.x - vm.x, vc.y - vm.y, vc.z - vm.z, vc.w - vm.w);
        } else {
            const float4 vm = *reinterpret_cast<const float4*>(pm + h4);
            const float4 vp = *reinterpret_cast<const float4*>(pp + h4);
            gx4 = make_float4(0.5f * (vp.x - vm.x), 0.5f * (vp.y - vm.y),
                              0.5f * (vp.z - vm.z), 0.5f * (vp.w - vm.w));
        }
        const float left  = pc[h4 > 0 ? h4 - 1 : 0];
        const float right = pc[h4 < 1020 ? h4 + 4 : 1023];
        const float gy0 = (h4 == 0)    ? vc.y - vc.x : 0.5f * (vc.y - left);
        const float gy1 = 0.5f * (vc.z - vc.x);
        const float gy2 = 0.5f * (vc.w - vc.y);
        const float gy3 = (h4 == 1020) ? vc.w - vc.z : 0.5f * (right - vc.z);

        sgx  += gx4.x + gx4.y + gx4.z + gx4.w;
        sgx2 += gx4.x * gx4.x + gx4.y * gx4.y + gx4.z * gx4.z + gx4.w * gx4.w;
        sgy  += gy0 + gy1 + gy2 + gy3;
        sgy2 += gy0 * gy0 + gy1 * gy1 + gy2 * gy2 + gy3 * gy3;

        ZPIX(vc.x, yv0);
        ZPIX(vc.y, yv0 + ystep);
        ZPIX(vc.z, yv0 + 2.0f * ystep);
        ZPIX(vc.w, yv0 + 3.0f * ystep);
    }

    WRED(a00, 0);  WRED(a11, 1);  WRED(a20, 2);  WRED(a22, 3);  WRED(a31, 4);
    WRED(a33, 5);  WRED(a40, 6);  WRED(a42, 7);  WRED(a44, 8);  WRED(a51, 9);
    WRED(a53, 10); WRED(a55, 11); WRED(a60, 12); WRED(a62, 13); WRED(a64, 14);
    WRED(a66, 15); WRED(a71, 16); WRED(a73, 17); WRED(a75, 18); WRED(a77, 19);
    WRED(a80, 20); WRED(a82, 21); WRED(a84, 22); WRED(a86, 23); WRED(a88, 24);
    WRED(a91, 25); WRED(a93, 26); WRED(a95, 27); WRED(a97, 28); WRED(a99, 29);
    WRED(b11, 30); WRED(b22, 31); WRED(b31, 32); WRED(b33, 33); WRED(b42, 34);
    WRED(b44, 35); WRED(b51, 36); WRED(b53, 37); WRED(b55, 38); WRED(b62, 39);
    WRED(b64, 40); WRED(b66, 41); WRED(b71, 42); WRED(b73, 43); WRED(b75, 44);
    WRED(b77, 45); WRED(b82, 46); WRED(b84, 47); WRED(b86, 48); WRED(b88, 49);
    WRED(b91, 50); WRED(b93, 51); WRED(b95, 52); WRED(b97, 53); WRED(b99, 54);
    WRED(sgx, 55); WRED(sgx2, 56); WRED(sgy, 57); WRED(sgy2, 58); WRED(cnt, 59);
    __syncthreads();
    if (tid < 60) {
        float sum = red[tid] + red[64 + tid] + red[128 + tid] + red[192 + tid];
        // Partial -> rf2 row (b, k0+2): disjoint from all blocks' read sets.
        float* pdst = (float*)(rf2 + ((long long)b * WR + k0 + 2) * 1024);
        pdst[tid] = sum;
    }
}

// ---------------------------------------------------------------------------
// Kernel D: sum 86 block-partials per batch, map moments -> coeffs, stats.
// ---------------------------------------------------------------------------
__device__ int moment_index(int p, int a, int is_cos) {
    int ai = 0;
    for (int pp = 0; pp < 10; ++pp)
        for (int aa = (pp & 1); aa <= pp; aa += 2) {
            if (is_cos && pp == p && aa == a) return ai;
            ++ai;
        }
    for (int pp = 1; pp < 10; ++pp)
        for (int aa = ((pp & 1) ? 1 : 2); aa <= pp; aa += 2) {
            if (!is_cos && pp == p && aa == a) return ai;
            ++ai;
        }
    return 0;
}

__device__ float factf(int n) {
    float f = 1.0f;
    for (int i = 2; i <= n; ++i) f *= (float)i;
    return f;
}

__global__ void finalize_kernel(const float* __restrict__ rf2f,
                                const float* __restrict__ magmax,
                                float* __restrict__ out) {
    __shared__ float abf[64];
    const int b = blockIdx.x;
    const int j = threadIdx.x;
    if (j < 60) {
        float s = 0.0f;
        for (int i = 0; i < 86; ++i)
            s += rf2f[((long long)b * WR + 6 * i + 2) * 2048 + j];
        abf[j] = s;
    }
    __syncthreads();
    if (j >= 60) return;
    const float NF = (float)NPIX;
    float val;
    if (j < 55) {
        int tt = j, n = 0;
        while (tt >= n + 1) { tt -= (n + 1); ++n; }
        int m = -n + 2 * tt;
        int am = m < 0 ? -m : m;
        float s = 0.0f;
        for (int k = 0; k <= (n - am) / 2; ++k) {
            float c = factf(n - k) /
                      (factf(k) * factf((n + am) / 2 - k) * factf((n - am) / 2 - k));
            if (k & 1) c = -c;
            int p = n - 2 * k;
            s += c * abf[moment_index(p, am, m >= 0 ? 1 : 0)];
        }
        val = s / abf[59];
    } else if (j == 55) {
        val = abf[55] / NF;
    } else if (j == 56) {
        val = abf[57] / NF;
    } else if (j == 57) {
        float sum = abf[55], sq = abf[56];
        val = sqrtf(fmaxf(0.0f, (sq - sum * sum / NF) / (NF - 1.0f)));
    } else if (j == 58) {
        float sum = abf[57], sq = abf[58];
        val = sqrtf(fmaxf(0.0f, (sq - sum * sum / NF) / (NF - 1.0f)));
    } else {
        val = magmax[b];
    }
    out[b * 60 + j] = val;
}

// ---------------------------------------------------------------------------
extern "C" void kernel_launch(void* const* d_in, const int* in_sizes, int n_in,
                              void* d_out, int out_size, void* d_ws, size_t ws_size,
                              hipStream_t stream) {
    (void)in_sizes; (void)n_in; (void)out_size; (void)ws_size;
    const float* x = (const float*)d_in[0];
    float* out = (float*)d_out;

    float* magmax = (float*)d_ws;                  // 32 floats (atomicMax target)
    float2* rf2 = (float2*)((char*)d_ws + 16384);  // [B][WR][H] float2 = 134.5 MB

    hipMemsetAsync(d_ws, 0, 16384, stream);
    row_fft_kernel<<<BATCH * 128, 256, 0, stream>>>(x, rf2);
    // 86 blocks x 6 useful rows cover the 513 k-rows of each batch.
    dim3 gridF(86, BATCH);
    fused_col_stats_kernel<<<gridF, 256, 0, stream>>>(rf2, magmax);
    finalize_kernel<<<BATCH, 64, 0, stream>>>((const float*)rf2, magmax, out);
}